// Round 7
// baseline (325.901 us; speedup 1.0000x reference)
//
#include <hip/hip_runtime.h>

// B=2, T=2048, C=1024, H=16, HD=64. Inputs f32, output f32.
// convert->bf16, QKV GEMM (MFMA + global_load_lds staging), RoPE+split (+V^T),
// flash attention (1 q-block/wave, 1024 blocks, XCD-grouped by head, swapped
// QK^T, in-register softmax), proj GEMM -> f32.
// ws plan (48 MiB):
//   [0,24M)  qkv   -> dead after rope; [0,8M) attn out, [8,10M) W_proj bf16
//   [24,32M) xb    -> dead after gemm1; reused as Q (B,H,T,64)
//   [32,38M) wqkvb -> dead after gemm1; reused as K (B,H,T,64) [32,40M)
//   [40,48M) V^T   (B,H,64,T)

typedef short  bf16x8 __attribute__((ext_vector_type(8)));
typedef float  f32x4  __attribute__((ext_vector_type(4)));
typedef unsigned short u16x4 __attribute__((ext_vector_type(4)));
typedef unsigned short u16x2 __attribute__((ext_vector_type(2)));

#define B_  2
#define T_  2048
#define H_  16
#define HD_ 64
#define NINF (-__builtin_inff())

static __device__ __forceinline__ unsigned short f2bf(float f) {
    union { float f; unsigned u; } v; v.f = f;
    unsigned r = v.u + 0x7fffu + ((v.u >> 16) & 1u);   // RNE
    return (unsigned short)(r >> 16);
}
static __device__ __forceinline__ float bf2f(unsigned short s) {
    union { unsigned u; float f; } v; v.u = ((unsigned)s) << 16;
    return v.f;
}

#define GLOAD_LDS16(gp, lp)                                                              \
    __builtin_amdgcn_global_load_lds((const __attribute__((address_space(1))) void*)(gp), \
                                     (__attribute__((address_space(3))) void*)(lp), 16, 0, 0)

// ---------------- f32 -> bf16 convert (vector x4) ----------------
__global__ void convert_f32_bf16(const float* __restrict__ in,
                                 unsigned short* __restrict__ out, int n4) {
    int i = blockIdx.x * blockDim.x + threadIdx.x;
    if (i >= n4) return;
    float4 f = ((const float4*)in)[i];
    u16x4 o; o[0] = f2bf(f.x); o[1] = f2bf(f.y); o[2] = f2bf(f.z); o[3] = f2bf(f.w);
    ((u16x4*)out)[i] = o;
}

// ---------------- GEMM (m97 structure): C[m][n] = sum_k A[m][k]*B[n][k] (+bias) ---
__global__ __launch_bounds__(256) void gemm_nt(const unsigned short* __restrict__ A,
                                               const unsigned short* __restrict__ Bm,
                                               void* __restrict__ Cm,
                                               const float* __restrict__ bias,
                                               int M, int N, int K, int out_f32) {
    __shared__ __align__(16) unsigned short As[128 * 32];
    __shared__ __align__(16) unsigned short Bs[128 * 32];
    const int tid  = threadIdx.x;
    const int w    = tid >> 6;
    const int lane = tid & 63;
    const int r    = lane & 15, g = lane >> 4;
    const int m0   = blockIdx.y * 128;
    const int n0   = blockIdx.x * 128;
    const int wm   = (w >> 1) * 64, wn = (w & 1) * 64;

    f32x4 acc[4][4];
#pragma unroll
    for (int i = 0; i < 4; i++)
#pragma unroll
        for (int j = 0; j < 4; j++) acc[i][j] = (f32x4){0.f, 0.f, 0.f, 0.f};

    const int u0 = tid, u1 = 256 + tid;
    const unsigned short* ga0 = A  + (size_t)(m0 + (u0 >> 2)) * K + (u0 & 3) * 8;
    const unsigned short* ga1 = A  + (size_t)(m0 + (u1 >> 2)) * K + (u1 & 3) * 8;
    const unsigned short* gb0 = Bm + (size_t)(n0 + (u0 >> 2)) * K + (u0 & 3) * 8;
    const unsigned short* gb1 = Bm + (size_t)(n0 + (u1 >> 2)) * K + (u1 & 3) * 8;
    unsigned short* la0 = &As[(w * 64) * 8];
    unsigned short* la1 = &As[(256 + w * 64) * 8];
    unsigned short* lb0 = &Bs[(w * 64) * 8];
    unsigned short* lb1 = &Bs[(256 + w * 64) * 8];

    for (int k0 = 0; k0 < K; k0 += 32) {
        __syncthreads();
        GLOAD_LDS16(ga0 + k0, la0);
        GLOAD_LDS16(ga1 + k0, la1);
        GLOAD_LDS16(gb0 + k0, lb0);
        GLOAD_LDS16(gb1 + k0, lb1);
        __syncthreads();

        bf16x8 a[4], b[4];
#pragma unroll
        for (int mi = 0; mi < 4; mi++) a[mi] = *(const bf16x8*)&As[(wm + mi * 16 + r) * 32 + 8 * g];
#pragma unroll
        for (int ni = 0; ni < 4; ni++) b[ni] = *(const bf16x8*)&Bs[(wn + ni * 16 + r) * 32 + 8 * g];
#pragma unroll
        for (int mi = 0; mi < 4; mi++)
#pragma unroll
            for (int ni = 0; ni < 4; ni++)
                acc[mi][ni] = __builtin_amdgcn_mfma_f32_16x16x32_bf16(a[mi], b[ni], acc[mi][ni], 0, 0, 0);
    }

#pragma unroll
    for (int mi = 0; mi < 4; mi++) {
        int row = m0 + wm + mi * 16 + 4 * g;
#pragma unroll
        for (int ni = 0; ni < 4; ni++) {
            int col = n0 + wn + ni * 16 + r;
            float bv = bias ? bias[col] : 0.f;
#pragma unroll
            for (int j = 0; j < 4; j++) {
                float v = acc[mi][ni][j] + bv;
                size_t idx = (size_t)(row + j) * N + col;
                if (out_f32) ((float*)Cm)[idx] = v;
                else         ((unsigned short*)Cm)[idx] = f2bf(v);
            }
        }
    }
}

// ---------------- RoPE + split qkv -> Q,K (B,H,T,HD) and V^T (B,H,HD,T) ----------------
__global__ void rope_split(const unsigned short* __restrict__ qkv,
                           const float* __restrict__ fa, const float* __restrict__ fb,
                           unsigned short* __restrict__ Qo, unsigned short* __restrict__ Ko,
                           unsigned short* __restrict__ Vt) {
    const float* fcos = (fa[0] > 0.5f) ? fa : fb;   // cos row at t=0 is all 1.0
    const float* fsin = (fa[0] > 0.5f) ? fb : fa;
    int tid = blockIdx.x * blockDim.x + threadIdx.x;
    int m  = tid / 1536;
    int d2 = tid - m * 1536;
    int n  = d2 * 2;
    int b  = m >> 11, t = m & 2047;
    u16x2 in = *(const u16x2*)(qkv + (size_t)m * 3072 + n);
    if (n < 2048) {
        int nn = n & 1023;
        int h = nn >> 6, d = nn & 63;
        int i = d >> 1;
        float c = fcos[t * 32 + i], s = fsin[t * 32 + i];
        float re = bf2f(in[0]), im = bf2f(in[1]);
        u16x2 o; o[0] = f2bf(re * c - im * s); o[1] = f2bf(re * s + im * c);
        unsigned short* dst = (n < 1024) ? Qo : Ko;
        *(u16x2*)(dst + ((size_t)((b * 16 + h) * 2048 + t)) * 64 + d) = o;
    } else {
        int nn = n - 2048;
        int h = nn >> 6, d = nn & 63;
        size_t base = ((size_t)((b * 16 + h) * 64 + d)) * 2048 + t;
        Vt[base]        = in[0];
        Vt[base + 2048] = in[1];
    }
}

// ---------------- flash attention: 1 q-block (16 rows) per wave ----------------
// 1024 blocks x 4 waves. Block j of head bh owns q-blocks {2j,127-2j,2j+1,126-2j}
// (uniform trip-count sum). XCD-grouped: all 32 blocks of one head on one XCD
// (K+V per XCD = 4 heads x 512 KB = 2 MB -> L2-resident).
static __device__ __forceinline__ bf16x8 ldv8(const unsigned short* p) {
    union { unsigned w[4]; bf16x8 v; } u;
    const unsigned* q = (const unsigned*)p;
    u.w[0] = q[0]; u.w[1] = q[1]; u.w[2] = q[8]; u.w[3] = q[9];   // 8B @ +0, 8B @ +16 elts
    return u.v;
}

static __device__ __forceinline__ void softmax64(const f32x4 s[4], int key0, int qrow,
                                                 bool diag, float& m, float& l,
                                                 f32x4 o[4], bf16x8& pf0, bf16x8& pf1, int g) {
    const float SCL = 0.125f * 1.4426950408889634f;   // HD^-0.5 * log2(e)
    float sv[16];
#pragma unroll
    for (int ks = 0; ks < 4; ks++)
#pragma unroll
        for (int j = 0; j < 4; j++) {
            float x = s[ks][j];
            if (diag && (key0 + ks * 16 + 4 * g + j > qrow)) x = NINF;
            sv[ks * 4 + j] = x;
        }
    float t8[8];
#pragma unroll
    for (int i = 0; i < 8; i++) t8[i] = fmaxf(sv[i], sv[i + 8]);
#pragma unroll
    for (int i = 0; i < 4; i++) t8[i] = fmaxf(t8[i], t8[i + 4]);
    float tm = fmaxf(fmaxf(t8[0], t8[1]), fmaxf(t8[2], t8[3]));
    tm = fmaxf(tm, __shfl_xor(tm, 16));
    tm = fmaxf(tm, __shfl_xor(tm, 32));
    float mnew  = fmaxf(m, tm);
    float alpha = exp2f((m - mnew) * SCL);
    float msc   = mnew * SCL;
    float p[16];
#pragma unroll
    for (int i = 0; i < 16; i++) p[i] = exp2f(__builtin_fmaf(sv[i], SCL, -msc));
    float ps0 = ((p[0] + p[1]) + (p[2] + p[3])) + ((p[4] + p[5]) + (p[6] + p[7]));
    float ps1 = ((p[8] + p[9]) + (p[10] + p[11])) + ((p[12] + p[13]) + (p[14] + p[15]));
    l = l * alpha + (ps0 + ps1);
    m = mnew;
#pragma unroll
    for (int ch = 0; ch < 4; ch++) o[ch] *= alpha;
    union { unsigned w[4]; bf16x8 v; } q0, q1;
    asm("v_cvt_pk_bf16_f32 %0, %1, %2" : "=v"(q0.w[0]) : "v"(p[0]),  "v"(p[1]));
    asm("v_cvt_pk_bf16_f32 %0, %1, %2" : "=v"(q0.w[1]) : "v"(p[2]),  "v"(p[3]));
    asm("v_cvt_pk_bf16_f32 %0, %1, %2" : "=v"(q0.w[2]) : "v"(p[4]),  "v"(p[5]));
    asm("v_cvt_pk_bf16_f32 %0, %1, %2" : "=v"(q0.w[3]) : "v"(p[6]),  "v"(p[7]));
    asm("v_cvt_pk_bf16_f32 %0, %1, %2" : "=v"(q1.w[0]) : "v"(p[8]),  "v"(p[9]));
    asm("v_cvt_pk_bf16_f32 %0, %1, %2" : "=v"(q1.w[1]) : "v"(p[10]), "v"(p[11]));
    asm("v_cvt_pk_bf16_f32 %0, %1, %2" : "=v"(q1.w[2]) : "v"(p[12]), "v"(p[13]));
    asm("v_cvt_pk_bf16_f32 %0, %1, %2" : "=v"(q1.w[3]) : "v"(p[14]), "v"(p[15]));
    pf0 = q0.v; pf1 = q1.v;
}

__global__ __launch_bounds__(256) void attn_fwd(const unsigned short* __restrict__ Q,
                                                const unsigned short* __restrict__ Kk,
                                                const unsigned short* __restrict__ Vt,
                                                unsigned short* __restrict__ O) {
    const int w    = threadIdx.x >> 6;
    const int lane = threadIdx.x & 63;
    const int l15  = lane & 15, g = lane >> 4;

    // XCD-grouped block id -> (bh, j): bid = (bh>>3)*256 + j*8 + (bh&7)
    const int bid = blockIdx.x;
    const int bh  = ((bid >> 8) << 3) | (bid & 7);
    const int j2  = (bid >> 3) & 31;
    // wave -> q-block: {2j, 127-2j, 2j+1, 126-2j}
    const int qb = (w == 0) ? 2 * j2 : (w == 1) ? 127 - 2 * j2
                 : (w == 2) ? 2 * j2 + 1 : 126 - 2 * j2;
    const int b = bh >> 4, h = bh & 15;

    const unsigned short* Qb = Q  + (size_t)bh * T_ * HD_;
    const unsigned short* Kb = Kk + (size_t)bh * T_ * HD_;
    const unsigned short* Vb = Vt + (size_t)bh * HD_ * T_;

    const int qrow = qb * 16 + l15;
    bf16x8 qf0 = *(const bf16x8*)(Qb + (size_t)qrow * 64 + 8 * g);
    bf16x8 qf1 = *(const bf16x8*)(Qb + (size_t)qrow * 64 + 32 + 8 * g);

    f32x4 o[4];
#pragma unroll
    for (int ch = 0; ch < 4; ch++) o[ch] = (f32x4){0, 0, 0, 0};
    float m2 = NINF, lsum = 0.f;
    const int dT = qb >> 2;                     // diagonal 64-key tile index

    for (int kt = 0; kt <= dT; ++kt) {
        const int key0 = kt * 64;
        // issue ALL loads (K + V) up front; V consumed after softmax (~300 cyc later)
        const unsigned short* kp = Kb + (size_t)(key0 + l15) * 64 + 8 * g;
        bf16x8 k0a = *(const bf16x8*)(kp);
        bf16x8 k0b = *(const bf16x8*)(kp + 32);
        bf16x8 k1a = *(const bf16x8*)(kp + 1024);
        bf16x8 k1b = *(const bf16x8*)(kp + 1056);
        bf16x8 k2a = *(const bf16x8*)(kp + 2048);
        bf16x8 k2b = *(const bf16x8*)(kp + 2080);
        bf16x8 k3a = *(const bf16x8*)(kp + 3072);
        bf16x8 k3b = *(const bf16x8*)(kp + 3104);
        bf16x8 va0[4], va1[4];
#pragma unroll
        for (int ch = 0; ch < 4; ch++) {
            const unsigned short* vp = Vb + (size_t)(16 * ch + l15) * 2048 + key0 + 4 * g;
            va0[ch] = ldv8(vp);
            va1[ch] = ldv8(vp + 32);
        }

        f32x4 s[4];
        f32x4 z = (f32x4){0, 0, 0, 0};
        s[0] = __builtin_amdgcn_mfma_f32_16x16x32_bf16(k0a, qf0, z, 0, 0, 0);
        s[0] = __builtin_amdgcn_mfma_f32_16x16x32_bf16(k0b, qf1, s[0], 0, 0, 0);
        s[1] = __builtin_amdgcn_mfma_f32_16x16x32_bf16(k1a, qf0, z, 0, 0, 0);
        s[1] = __builtin_amdgcn_mfma_f32_16x16x32_bf16(k1b, qf1, s[1], 0, 0, 0);
        s[2] = __builtin_amdgcn_mfma_f32_16x16x32_bf16(k2a, qf0, z, 0, 0, 0);
        s[2] = __builtin_amdgcn_mfma_f32_16x16x32_bf16(k2b, qf1, s[2], 0, 0, 0);
        s[3] = __builtin_amdgcn_mfma_f32_16x16x32_bf16(k3a, qf0, z, 0, 0, 0);
        s[3] = __builtin_amdgcn_mfma_f32_16x16x32_bf16(k3b, qf1, s[3], 0, 0, 0);

        bf16x8 pf0, pf1;
        softmax64(s, key0, qrow, kt == dT, m2, lsum, o, pf0, pf1, g);

#pragma unroll
        for (int ch = 0; ch < 4; ch++) {
            o[ch] = __builtin_amdgcn_mfma_f32_16x16x32_bf16(va0[ch], pf0, o[ch], 0, 0, 0);
            o[ch] = __builtin_amdgcn_mfma_f32_16x16x32_bf16(va1[ch], pf1, o[ch], 0, 0, 0);
        }
    }

    lsum += __shfl_xor(lsum, 16);
    lsum += __shfl_xor(lsum, 32);
    float inv = 1.f / lsum;

    size_t obase = (((size_t)b * T_ + qrow) * H_ + h) * HD_;
#pragma unroll
    for (int ch = 0; ch < 4; ch++) {
        int d0 = 16 * ch + 4 * g;
        u16x4 ov;
#pragma unroll
        for (int jj = 0; jj < 4; jj++) ov[jj] = f2bf(o[ch][jj] * inv);
        *(u16x4*)(O + obase + d0) = ov;
    }
}

extern "C" void kernel_launch(void* const* d_in, const int* in_sizes, int n_in,
                              void* d_out, int out_size, void* d_ws, size_t ws_size,
                              hipStream_t stream) {
    (void)out_size;
    const float *x = nullptr, *wqkv = nullptr, *wproj = nullptr, *bproj = nullptr;
    const float *fa = nullptr, *fb = nullptr;
    for (int i = 0; i < n_in; i++) {
        switch (in_sizes[i]) {
            case 4194304: x     = (const float*)d_in[i]; break;
            case 3145728: wqkv  = (const float*)d_in[i]; break;
            case 1048576: wproj = (const float*)d_in[i]; break;
            case 1024:    bproj = (const float*)d_in[i]; break;
            case 65536:   if (!fa) fa = (const float*)d_in[i]; else fb = (const float*)d_in[i]; break;
            default: break;
        }
    }
    if (!x || !wqkv || !wproj || !bproj || !fa || !fb) return;
    if (ws_size < (size_t)48 * 1024 * 1024) return;

    char* ws = (char*)d_ws;
    const size_t MB = 1024 * 1024;
    unsigned short* qkv    = (unsigned short*)(ws);            // [0,24M)
    unsigned short* oat    = (unsigned short*)(ws);            // [0,8M)   (after rope)
    unsigned short* wprojb = (unsigned short*)(ws + 8  * MB);  // [8,10M)  (after rope)
    unsigned short* xb     = (unsigned short*)(ws + 24 * MB);  // [24,32M)
    unsigned short* wqkvb  = (unsigned short*)(ws + 32 * MB);  // [32,38M)
    unsigned short* qro    = (unsigned short*)(ws + 24 * MB);  // [24,32M)
    unsigned short* kro    = (unsigned short*)(ws + 32 * MB);  // [32,40M)
    unsigned short* vt     = (unsigned short*)(ws + 40 * MB);  // [40,48M)

    convert_f32_bf16<<<4096, 256, 0, stream>>>(x,    xb,    4194304 / 4);
    convert_f32_bf16<<<3072, 256, 0, stream>>>(wqkv, wqkvb, 3145728 / 4);

    gemm_nt<<<dim3(3072 / 128, 4096 / 128), 256, 0, stream>>>(xb, wqkvb, qkv, nullptr,
                                                              4096, 3072, 1024, 0);

    rope_split<<<(4096 * 1536) / 256, 256, 0, stream>>>(qkv, fa, fb, qro, kro, vt);

    convert_f32_bf16<<<1024, 256, 0, stream>>>(wproj, wprojb, 1048576 / 4);

    attn_fwd<<<1024, 256, 0, stream>>>(qro, kro, vt, oat);

    gemm_nt<<<dim3(1024 / 128, 4096 / 128), 256, 0, stream>>>(oat, wprojb, d_out, bproj,
                                                              4096, 1024, 1024, 1);
}

// Round 8
// 169.188 us; speedup vs baseline: 1.9263x; 1.9263x over previous
//
#include <hip/hip_runtime.h>

// B=2, T=2048, C=1024, H=16, HD=64. Inputs f32, output f32.
// convert->bf16, QKV GEMM (MFMA + global_load_lds), RoPE+split (+V^T),
// block-cooperative LDS flash attention (causal-paired q-ranges, shared K/V
// tiles, XOR-swizzled stage/read, swapped-QK^T MFMA), proj GEMM -> f32.
// ws plan (48 MiB):
//   [0,24M)  qkv   -> dead after rope; [0,8M) attn out, [8,10M) W_proj bf16
//   [24,32M) xb    -> dead after gemm1; reused as Q (B,H,T,64)
//   [32,38M) wqkvb -> dead after gemm1; reused as K (B,H,T,64) [32,40M)
//   [40,48M) V^T   (B,H,64,T)

typedef short  bf16x8 __attribute__((ext_vector_type(8)));
typedef float  f32x4  __attribute__((ext_vector_type(4)));
typedef unsigned short u16x4 __attribute__((ext_vector_type(4)));
typedef unsigned short u16x2 __attribute__((ext_vector_type(2)));

#define B_  2
#define T_  2048
#define H_  16
#define HD_ 64
#define NINF (-__builtin_inff())

static __device__ __forceinline__ unsigned short f2bf(float f) {
    union { float f; unsigned u; } v; v.f = f;
    unsigned r = v.u + 0x7fffu + ((v.u >> 16) & 1u);   // RNE
    return (unsigned short)(r >> 16);
}
static __device__ __forceinline__ float bf2f(unsigned short s) {
    union { unsigned u; float f; } v; v.u = ((unsigned)s) << 16;
    return v.f;
}

#define GLOAD_LDS16(gp, lp)                                                              \
    __builtin_amdgcn_global_load_lds((const __attribute__((address_space(1))) void*)(gp), \
                                     (__attribute__((address_space(3))) void*)(lp), 16, 0, 0)

// ---------------- f32 -> bf16 convert (vector x4) ----------------
__global__ void convert_f32_bf16(const float* __restrict__ in,
                                 unsigned short* __restrict__ out, int n4) {
    int i = blockIdx.x * blockDim.x + threadIdx.x;
    if (i >= n4) return;
    float4 f = ((const float4*)in)[i];
    u16x4 o; o[0] = f2bf(f.x); o[1] = f2bf(f.y); o[2] = f2bf(f.z); o[3] = f2bf(f.w);
    ((u16x4*)out)[i] = o;
}

// ---------------- GEMM (m97 structure): C[m][n] = sum_k A[m][k]*B[n][k] (+bias) ---
__global__ __launch_bounds__(256) void gemm_nt(const unsigned short* __restrict__ A,
                                               const unsigned short* __restrict__ Bm,
                                               void* __restrict__ Cm,
                                               const float* __restrict__ bias,
                                               int M, int N, int K, int out_f32) {
    __shared__ __align__(16) unsigned short As[128 * 32];
    __shared__ __align__(16) unsigned short Bs[128 * 32];
    const int tid  = threadIdx.x;
    const int w    = tid >> 6;
    const int lane = tid & 63;
    const int r    = lane & 15, g = lane >> 4;
    const int m0   = blockIdx.y * 128;
    const int n0   = blockIdx.x * 128;
    const int wm   = (w >> 1) * 64, wn = (w & 1) * 64;

    f32x4 acc[4][4];
#pragma unroll
    for (int i = 0; i < 4; i++)
#pragma unroll
        for (int j = 0; j < 4; j++) acc[i][j] = (f32x4){0.f, 0.f, 0.f, 0.f};

    const int u0 = tid, u1 = 256 + tid;
    const unsigned short* ga0 = A  + (size_t)(m0 + (u0 >> 2)) * K + (u0 & 3) * 8;
    const unsigned short* ga1 = A  + (size_t)(m0 + (u1 >> 2)) * K + (u1 & 3) * 8;
    const unsigned short* gb0 = Bm + (size_t)(n0 + (u0 >> 2)) * K + (u0 & 3) * 8;
    const unsigned short* gb1 = Bm + (size_t)(n0 + (u1 >> 2)) * K + (u1 & 3) * 8;
    unsigned short* la0 = &As[(w * 64) * 8];
    unsigned short* la1 = &As[(256 + w * 64) * 8];
    unsigned short* lb0 = &Bs[(w * 64) * 8];
    unsigned short* lb1 = &Bs[(256 + w * 64) * 8];

    for (int k0 = 0; k0 < K; k0 += 32) {
        __syncthreads();
        GLOAD_LDS16(ga0 + k0, la0);
        GLOAD_LDS16(ga1 + k0, la1);
        GLOAD_LDS16(gb0 + k0, lb0);
        GLOAD_LDS16(gb1 + k0, lb1);
        __syncthreads();

        bf16x8 a[4], b[4];
#pragma unroll
        for (int mi = 0; mi < 4; mi++) a[mi] = *(const bf16x8*)&As[(wm + mi * 16 + r) * 32 + 8 * g];
#pragma unroll
        for (int ni = 0; ni < 4; ni++) b[ni] = *(const bf16x8*)&Bs[(wn + ni * 16 + r) * 32 + 8 * g];
#pragma unroll
        for (int mi = 0; mi < 4; mi++)
#pragma unroll
            for (int ni = 0; ni < 4; ni++)
                acc[mi][ni] = __builtin_amdgcn_mfma_f32_16x16x32_bf16(a[mi], b[ni], acc[mi][ni], 0, 0, 0);
    }

#pragma unroll
    for (int mi = 0; mi < 4; mi++) {
        int row = m0 + wm + mi * 16 + 4 * g;
#pragma unroll
        for (int ni = 0; ni < 4; ni++) {
            int col = n0 + wn + ni * 16 + r;
            float bv = bias ? bias[col] : 0.f;
#pragma unroll
            for (int j = 0; j < 4; j++) {
                float v = acc[mi][ni][j] + bv;
                size_t idx = (size_t)(row + j) * N + col;
                if (out_f32) ((float*)Cm)[idx] = v;
                else         ((unsigned short*)Cm)[idx] = f2bf(v);
            }
        }
    }
}

// ---------------- RoPE + split qkv -> Q,K (B,H,T,HD) and V^T (B,H,HD,T) ----------------
__global__ void rope_split(const unsigned short* __restrict__ qkv,
                           const float* __restrict__ fa, const float* __restrict__ fb,
                           unsigned short* __restrict__ Qo, unsigned short* __restrict__ Ko,
                           unsigned short* __restrict__ Vt) {
    const float* fcos = (fa[0] > 0.5f) ? fa : fb;   // cos row at t=0 is all 1.0
    const float* fsin = (fa[0] > 0.5f) ? fb : fa;
    int tid = blockIdx.x * blockDim.x + threadIdx.x;
    int m  = tid / 1536;
    int d2 = tid - m * 1536;
    int n  = d2 * 2;
    int b  = m >> 11, t = m & 2047;
    u16x2 in = *(const u16x2*)(qkv + (size_t)m * 3072 + n);
    if (n < 2048) {
        int nn = n & 1023;
        int h = nn >> 6, d = nn & 63;
        int i = d >> 1;
        float c = fcos[t * 32 + i], s = fsin[t * 32 + i];
        float re = bf2f(in[0]), im = bf2f(in[1]);
        u16x2 o; o[0] = f2bf(re * c - im * s); o[1] = f2bf(re * s + im * c);
        unsigned short* dst = (n < 1024) ? Qo : Ko;
        *(u16x2*)(dst + ((size_t)((b * 16 + h) * 2048 + t)) * 64 + d) = o;
    } else {
        int nn = n - 2048;
        int h = nn >> 6, d = nn & 63;
        size_t base = ((size_t)((b * 16 + h) * 64 + d)) * 2048 + t;
        Vt[base]        = in[0];
        Vt[base + 2048] = in[1];
    }
}

// ---------------- block-cooperative LDS flash attention ----------------
// 512 blocks = 32 heads x 16 causal pairs. Block p of head bh owns q-rows
// [64p, 64p+64) (lo) and [2048-64(p+1), 2048-64p) (hi); wave w takes 16 rows
// of each. K/V^T 64-key tiles staged in LDS via global_load_lds with
// XOR-swizzled SOURCE (linear dest) and the same XOR on ds_read (involution).
// All branches block-uniform -> barriers safe, no wave drain.
static __device__ __forceinline__ int swzb(int row, int chunk) {   // LDS byte offset
    return (row << 7) + ((chunk ^ (row & 7)) << 4);
}
static __device__ __forceinline__ bf16x8 pack2(uint2 a, uint2 b) {
    union { unsigned w[4]; bf16x8 v; } u;
    u.w[0] = a.x; u.w[1] = a.y; u.w[2] = b.x; u.w[3] = b.y;
    return u.v;
}

static __device__ __forceinline__ void softmax64(const f32x4 s[4], int key0, int qrow,
                                                 bool diag, float& m, float& l,
                                                 f32x4 o[4], bf16x8& pf0, bf16x8& pf1, int g) {
    const float SCL = 0.125f * 1.4426950408889634f;   // HD^-0.5 * log2(e)
    float sv[16];
#pragma unroll
    for (int ks = 0; ks < 4; ks++)
#pragma unroll
        for (int j = 0; j < 4; j++) {
            float x = s[ks][j];
            if (diag && (key0 + ks * 16 + 4 * g + j > qrow)) x = NINF;
            sv[ks * 4 + j] = x;
        }
    float t8[8];
#pragma unroll
    for (int i = 0; i < 8; i++) t8[i] = fmaxf(sv[i], sv[i + 8]);
#pragma unroll
    for (int i = 0; i < 4; i++) t8[i] = fmaxf(t8[i], t8[i + 4]);
    float tm = fmaxf(fmaxf(t8[0], t8[1]), fmaxf(t8[2], t8[3]));
    tm = fmaxf(tm, __shfl_xor(tm, 16));
    tm = fmaxf(tm, __shfl_xor(tm, 32));
    float mnew  = fmaxf(m, tm);
    float alpha = exp2f((m - mnew) * SCL);
    float msc   = mnew * SCL;
    float p[16];
#pragma unroll
    for (int i = 0; i < 16; i++) p[i] = exp2f(__builtin_fmaf(sv[i], SCL, -msc));
    float ps0 = ((p[0] + p[1]) + (p[2] + p[3])) + ((p[4] + p[5]) + (p[6] + p[7]));
    float ps1 = ((p[8] + p[9]) + (p[10] + p[11])) + ((p[12] + p[13]) + (p[14] + p[15]));
    l = l * alpha + (ps0 + ps1);
    m = mnew;
#pragma unroll
    for (int ch = 0; ch < 4; ch++) o[ch] *= alpha;
    union { unsigned w[4]; bf16x8 v; } q0, q1;
    asm("v_cvt_pk_bf16_f32 %0, %1, %2" : "=v"(q0.w[0]) : "v"(p[0]),  "v"(p[1]));
    asm("v_cvt_pk_bf16_f32 %0, %1, %2" : "=v"(q0.w[1]) : "v"(p[2]),  "v"(p[3]));
    asm("v_cvt_pk_bf16_f32 %0, %1, %2" : "=v"(q0.w[2]) : "v"(p[4]),  "v"(p[5]));
    asm("v_cvt_pk_bf16_f32 %0, %1, %2" : "=v"(q0.w[3]) : "v"(p[6]),  "v"(p[7]));
    asm("v_cvt_pk_bf16_f32 %0, %1, %2" : "=v"(q1.w[0]) : "v"(p[8]),  "v"(p[9]));
    asm("v_cvt_pk_bf16_f32 %0, %1, %2" : "=v"(q1.w[1]) : "v"(p[10]), "v"(p[11]));
    asm("v_cvt_pk_bf16_f32 %0, %1, %2" : "=v"(q1.w[2]) : "v"(p[12]), "v"(p[13]));
    asm("v_cvt_pk_bf16_f32 %0, %1, %2" : "=v"(q1.w[3]) : "v"(p[14]), "v"(p[15]));
    pf0 = q0.v; pf1 = q1.v;
}

__global__ __launch_bounds__(256) void attn_fwd(const unsigned short* __restrict__ Q,
                                                const unsigned short* __restrict__ Kk,
                                                const unsigned short* __restrict__ Vt,
                                                unsigned short* __restrict__ O) {
    __shared__ __align__(16) unsigned short Ks[4096];   // 64 keys x 64 d (swizzled)
    __shared__ __align__(16) unsigned short Vs[4096];   // 64 d x 64 keys (swizzled)

    const int w    = threadIdx.x >> 6;
    const int lane = threadIdx.x & 63;
    const int l15  = lane & 15, g = lane >> 4;

    // bid = ((bh>>3)*16 + p)*8 + (bh&7)  -> same-head blocks on one XCD
    const int bid = blockIdx.x;
    const int idx = bid >> 3;
    const int p   = idx & 15;
    const int bh  = ((idx >> 4) << 3) | (bid & 7);
    const int b   = bh >> 4, h = bh & 15;

    const unsigned short* Qb = Q  + (size_t)bh * T_ * HD_;
    const unsigned short* Kb = Kk + (size_t)bh * T_ * HD_;
    const unsigned short* Vb = Vt + (size_t)bh * HD_ * T_;

    const int qLo = p * 64 + 16 * w + l15;
    const int qHi = 2048 - 64 * (p + 1) + 16 * w + l15;
    bf16x8 qlo0 = *(const bf16x8*)(Qb + (size_t)qLo * 64 + 8 * g);
    bf16x8 qlo1 = *(const bf16x8*)(Qb + (size_t)qLo * 64 + 32 + 8 * g);
    bf16x8 qhi0 = *(const bf16x8*)(Qb + (size_t)qHi * 64 + 8 * g);
    bf16x8 qhi1 = *(const bf16x8*)(Qb + (size_t)qHi * 64 + 32 + 8 * g);

    f32x4 oLo[4], oHi[4];
#pragma unroll
    for (int ch = 0; ch < 4; ch++) { oLo[ch] = (f32x4){0,0,0,0}; oHi[ch] = (f32x4){0,0,0,0}; }
    float mLo = NINF, lLo = 0.f, mHi = NINF, lHi = 0.f;

    // staging: unit u -> LDS elems [u*8,u*8+8) = tile slot (row u>>3, chunk u&7);
    // source chunk = (u&7) ^ (row&7)  => LDS slot (r,c) holds global chunk (r, c^(r&7)).
    const int t  = threadIdx.x;
    const int r0 = t >> 3;                      // 0..31
    const int cs = (t & 7) ^ (r0 & 7);
    const unsigned short* sK = Kb + (size_t)r0 * 64 + cs * 8;     // + key0*64 per tile
    const unsigned short* sV = Vb + (size_t)r0 * 2048 + cs * 8;   // + key0 per tile
    unsigned short* dK0 = &Ks[t * 8];
    unsigned short* dK1 = &Ks[(256 + t) * 8];
    unsigned short* dV0 = &Vs[t * 8];
    unsigned short* dV1 = &Vs[(256 + t) * 8];

    const int ktEnd = 31 - p;      // hi diagonal tile index; lo diagonal at kt==p
    for (int kt = 0; kt <= ktEnd; ++kt) {
        const int key0 = kt * 64;
        __syncthreads();                               // prior tile's reads done
        GLOAD_LDS16(sK + (size_t)key0 * 64,            dK0);   // K rows key0+r0
        GLOAD_LDS16(sK + (size_t)(key0 + 32) * 64,     dK1);   // K rows key0+32+r0
        GLOAD_LDS16(sV + key0,                         dV0);   // V^T rows r0
        GLOAD_LDS16(sV + 32 * 2048 + key0,             dV1);   // V^T rows 32+r0
        __syncthreads();                               // vmcnt drained at barrier

        // K fragments (shared by both streams): rows ks*16+l15, chunks {g, 4+g}
        bf16x8 kf[4][2];
#pragma unroll
        for (int ks = 0; ks < 4; ks++) {
            int rK = ks * 16 + l15;
            kf[ks][0] = *(const bf16x8*)((const char*)Ks + swzb(rK, g));
            kf[ks][1] = *(const bf16x8*)((const char*)Ks + swzb(rK, 4 + g));
        }
        // V^T fragments: rows 16ch+l15; b64 at byte (g&1)*8 in chunks {s*2 + (g>>1)}
        bf16x8 va[4][2];
#pragma unroll
        for (int ch = 0; ch < 4; ch++) {
            int rV = 16 * ch + l15;
            int wo = (g & 1) * 8;
            uint2 s0 = *(const uint2*)((const char*)Vs + swzb(rV, (g >> 1))     + wo);
            uint2 s1 = *(const uint2*)((const char*)Vs + swzb(rV, 2 + (g >> 1)) + wo);
            uint2 s2 = *(const uint2*)((const char*)Vs + swzb(rV, 4 + (g >> 1)) + wo);
            uint2 s3 = *(const uint2*)((const char*)Vs + swzb(rV, 6 + (g >> 1)) + wo);
            va[ch][0] = pack2(s0, s1);   // key slots 4g+j, 16+4g+j
            va[ch][1] = pack2(s2, s3);   // key slots 32+4g+j, 48+4g+j
        }

        f32x4 z = (f32x4){0, 0, 0, 0};
        // hi stream (always active)
        {
            f32x4 s[4];
#pragma unroll
            for (int ks = 0; ks < 4; ks++) {
                s[ks] = __builtin_amdgcn_mfma_f32_16x16x32_bf16(kf[ks][0], qhi0, z, 0, 0, 0);
                s[ks] = __builtin_amdgcn_mfma_f32_16x16x32_bf16(kf[ks][1], qhi1, s[ks], 0, 0, 0);
            }
            bf16x8 pf0, pf1;
            softmax64(s, key0, qHi, kt == ktEnd, mHi, lHi, oHi, pf0, pf1, g);
#pragma unroll
            for (int ch = 0; ch < 4; ch++) {
                oHi[ch] = __builtin_amdgcn_mfma_f32_16x16x32_bf16(va[ch][0], pf0, oHi[ch], 0, 0, 0);
                oHi[ch] = __builtin_amdgcn_mfma_f32_16x16x32_bf16(va[ch][1], pf1, oHi[ch], 0, 0, 0);
            }
        }
        // lo stream (block-uniform branch)
        if (kt <= p) {
            f32x4 s[4];
#pragma unroll
            for (int ks = 0; ks < 4; ks++) {
                s[ks] = __builtin_amdgcn_mfma_f32_16x16x32_bf16(kf[ks][0], qlo0, z, 0, 0, 0);
                s[ks] = __builtin_amdgcn_mfma_f32_16x16x32_bf16(kf[ks][1], qlo1, s[ks], 0, 0, 0);
            }
            bf16x8 pf0, pf1;
            softmax64(s, key0, qLo, kt == p, mLo, lLo, oLo, pf0, pf1, g);
#pragma unroll
            for (int ch = 0; ch < 4; ch++) {
                oLo[ch] = __builtin_amdgcn_mfma_f32_16x16x32_bf16(va[ch][0], pf0, oLo[ch], 0, 0, 0);
                oLo[ch] = __builtin_amdgcn_mfma_f32_16x16x32_bf16(va[ch][1], pf1, oLo[ch], 0, 0, 0);
            }
        }
    }

    lLo += __shfl_xor(lLo, 16); lLo += __shfl_xor(lLo, 32);
    lHi += __shfl_xor(lHi, 16); lHi += __shfl_xor(lHi, 32);
    float invLo = 1.f / lLo, invHi = 1.f / lHi;

    size_t oLoB = (((size_t)b * T_ + qLo) * H_ + h) * HD_;
    size_t oHiB = (((size_t)b * T_ + qHi) * H_ + h) * HD_;
#pragma unroll
    for (int ch = 0; ch < 4; ch++) {
        int d0 = 16 * ch + 4 * g;
        u16x4 va_, vb_;
#pragma unroll
        for (int jj = 0; jj < 4; jj++) {
            va_[jj] = f2bf(oLo[ch][jj] * invLo);
            vb_[jj] = f2bf(oHi[ch][jj] * invHi);
        }
        *(u16x4*)(O + oLoB + d0) = va_;
        *(u16x4*)(O + oHiB + d0) = vb_;
    }
}

extern "C" void kernel_launch(void* const* d_in, const int* in_sizes, int n_in,
                              void* d_out, int out_size, void* d_ws, size_t ws_size,
                              hipStream_t stream) {
    (void)out_size;
    const float *x = nullptr, *wqkv = nullptr, *wproj = nullptr, *bproj = nullptr;
    const float *fa = nullptr, *fb = nullptr;
    for (int i = 0; i < n_in; i++) {
        switch (in_sizes[i]) {
            case 4194304: x     = (const float*)d_in[i]; break;
            case 3145728: wqkv  = (const float*)d_in[i]; break;
            case 1048576: wproj = (const float*)d_in[i]; break;
            case 1024:    bproj = (const float*)d_in[i]; break;
            case 65536:   if (!fa) fa = (const float*)d_in[i]; else fb = (const float*)d_in[i]; break;
            default: break;
        }
    }
    if (!x || !wqkv || !wproj || !bproj || !fa || !fb) return;
    if (ws_size < (size_t)48 * 1024 * 1024) return;

    char* ws = (char*)d_ws;
    const size_t MB = 1024 * 1024;
    unsigned short* qkv    = (unsigned short*)(ws);            // [0,24M)
    unsigned short* oat    = (unsigned short*)(ws);            // [0,8M)   (after rope)
    unsigned short* wprojb = (unsigned short*)(ws + 8  * MB);  // [8,10M)  (after rope)
    unsigned short* xb     = (unsigned short*)(ws + 24 * MB);  // [24,32M)
    unsigned short* wqkvb  = (unsigned short*)(ws + 32 * MB);  // [32,38M)
    unsigned short* qro    = (unsigned short*)(ws + 24 * MB);  // [24,32M)
    unsigned short* kro    = (unsigned short*)(ws + 32 * MB);  // [32,40M)
    unsigned short* vt     = (unsigned short*)(ws + 40 * MB);  // [40,48M)

    convert_f32_bf16<<<4096, 256, 0, stream>>>(x,    xb,    4194304 / 4);
    convert_f32_bf16<<<3072, 256, 0, stream>>>(wqkv, wqkvb, 3145728 / 4);

    gemm_nt<<<dim3(3072 / 128, 4096 / 128), 256, 0, stream>>>(xb, wqkvb, qkv, nullptr,
                                                              4096, 3072, 1024, 0);

    rope_split<<<(4096 * 1536) / 256, 256, 0, stream>>>(qkv, fa, fb, qro, kro, vt);

    convert_f32_bf16<<<1024, 256, 0, stream>>>(wproj, wprojb, 1048576 / 4);

    attn_fwd<<<512, 256, 0, stream>>>(qro, kro, vt, oat);

    gemm_nt<<<dim3(1024 / 128, 4096 / 128), 256, 0, stream>>>(oat, wprojb, d_out, bproj,
                                                              4096, 1024, 1024, 1);
}

// Round 9
// 168.155 us; speedup vs baseline: 1.9381x; 1.0061x over previous
//
#include <hip/hip_runtime.h>

// B=2, T=2048, C=1024, H=16, HD=64. Inputs f32, output f32.
// convert->bf16, QKV GEMM (MFMA + global_load_lds), RoPE+split (+V^T),
// block-cooperative LDS flash attention (causal-paired q-ranges, double-
// buffered K/V tiles, complementary-p CU pairing, exact defer-max softmax,
// swapped-QK^T MFMA), proj GEMM -> f32.
// ws plan (48 MiB):
//   [0,24M)  qkv   -> dead after rope; [0,8M) attn out, [8,10M) W_proj bf16
//   [24,32M) xb    -> dead after gemm1; reused as Q (B,H,T,64)
//   [32,38M) wqkvb -> dead after gemm1; reused as K (B,H,T,64) [32,40M)
//   [40,48M) V^T   (B,H,64,T)

typedef short  bf16x8 __attribute__((ext_vector_type(8)));
typedef float  f32x4  __attribute__((ext_vector_type(4)));
typedef unsigned short u16x4 __attribute__((ext_vector_type(4)));
typedef unsigned short u16x2 __attribute__((ext_vector_type(2)));

#define B_  2
#define T_  2048
#define H_  16
#define HD_ 64
#define NINF (-__builtin_inff())

static __device__ __forceinline__ unsigned short f2bf(float f) {
    union { float f; unsigned u; } v; v.f = f;
    unsigned r = v.u + 0x7fffu + ((v.u >> 16) & 1u);   // RNE
    return (unsigned short)(r >> 16);
}
static __device__ __forceinline__ float bf2f(unsigned short s) {
    union { unsigned u; float f; } v; v.u = ((unsigned)s) << 16;
    return v.f;
}

#define GLOAD_LDS16(gp, lp)                                                              \
    __builtin_amdgcn_global_load_lds((const __attribute__((address_space(1))) void*)(gp), \
                                     (__attribute__((address_space(3))) void*)(lp), 16, 0, 0)

// ---------------- f32 -> bf16 convert (vector x4) ----------------
__global__ void convert_f32_bf16(const float* __restrict__ in,
                                 unsigned short* __restrict__ out, int n4) {
    int i = blockIdx.x * blockDim.x + threadIdx.x;
    if (i >= n4) return;
    float4 f = ((const float4*)in)[i];
    u16x4 o; o[0] = f2bf(f.x); o[1] = f2bf(f.y); o[2] = f2bf(f.z); o[3] = f2bf(f.w);
    ((u16x4*)out)[i] = o;
}

// ---------------- GEMM (m97 structure): C[m][n] = sum_k A[m][k]*B[n][k] (+bias) ---
__global__ __launch_bounds__(256) void gemm_nt(const unsigned short* __restrict__ A,
                                               const unsigned short* __restrict__ Bm,
                                               void* __restrict__ Cm,
                                               const float* __restrict__ bias,
                                               int M, int N, int K, int out_f32) {
    __shared__ __align__(16) unsigned short As[128 * 32];
    __shared__ __align__(16) unsigned short Bs[128 * 32];
    const int tid  = threadIdx.x;
    const int w    = tid >> 6;
    const int lane = tid & 63;
    const int r    = lane & 15, g = lane >> 4;
    const int m0   = blockIdx.y * 128;
    const int n0   = blockIdx.x * 128;
    const int wm   = (w >> 1) * 64, wn = (w & 1) * 64;

    f32x4 acc[4][4];
#pragma unroll
    for (int i = 0; i < 4; i++)
#pragma unroll
        for (int j = 0; j < 4; j++) acc[i][j] = (f32x4){0.f, 0.f, 0.f, 0.f};

    const int u0 = tid, u1 = 256 + tid;
    const unsigned short* ga0 = A  + (size_t)(m0 + (u0 >> 2)) * K + (u0 & 3) * 8;
    const unsigned short* ga1 = A  + (size_t)(m0 + (u1 >> 2)) * K + (u1 & 3) * 8;
    const unsigned short* gb0 = Bm + (size_t)(n0 + (u0 >> 2)) * K + (u0 & 3) * 8;
    const unsigned short* gb1 = Bm + (size_t)(n0 + (u1 >> 2)) * K + (u1 & 3) * 8;
    unsigned short* la0 = &As[(w * 64) * 8];
    unsigned short* la1 = &As[(256 + w * 64) * 8];
    unsigned short* lb0 = &Bs[(w * 64) * 8];
    unsigned short* lb1 = &Bs[(256 + w * 64) * 8];

    for (int k0 = 0; k0 < K; k0 += 32) {
        __syncthreads();
        GLOAD_LDS16(ga0 + k0, la0);
        GLOAD_LDS16(ga1 + k0, la1);
        GLOAD_LDS16(gb0 + k0, lb0);
        GLOAD_LDS16(gb1 + k0, lb1);
        __syncthreads();

        bf16x8 a[4], b[4];
#pragma unroll
        for (int mi = 0; mi < 4; mi++) a[mi] = *(const bf16x8*)&As[(wm + mi * 16 + r) * 32 + 8 * g];
#pragma unroll
        for (int ni = 0; ni < 4; ni++) b[ni] = *(const bf16x8*)&Bs[(wn + ni * 16 + r) * 32 + 8 * g];
#pragma unroll
        for (int mi = 0; mi < 4; mi++)
#pragma unroll
            for (int ni = 0; ni < 4; ni++)
                acc[mi][ni] = __builtin_amdgcn_mfma_f32_16x16x32_bf16(a[mi], b[ni], acc[mi][ni], 0, 0, 0);
    }

#pragma unroll
    for (int mi = 0; mi < 4; mi++) {
        int row = m0 + wm + mi * 16 + 4 * g;
#pragma unroll
        for (int ni = 0; ni < 4; ni++) {
            int col = n0 + wn + ni * 16 + r;
            float bv = bias ? bias[col] : 0.f;
#pragma unroll
            for (int j = 0; j < 4; j++) {
                float v = acc[mi][ni][j] + bv;
                size_t idx = (size_t)(row + j) * N + col;
                if (out_f32) ((float*)Cm)[idx] = v;
                else         ((unsigned short*)Cm)[idx] = f2bf(v);
            }
        }
    }
}

// ---------------- RoPE + split qkv -> Q,K (B,H,T,HD) and V^T (B,H,HD,T) ----------------
__global__ void rope_split(const unsigned short* __restrict__ qkv,
                           const float* __restrict__ fa, const float* __restrict__ fb,
                           unsigned short* __restrict__ Qo, unsigned short* __restrict__ Ko,
                           unsigned short* __restrict__ Vt) {
    const float* fcos = (fa[0] > 0.5f) ? fa : fb;   // cos row at t=0 is all 1.0
    const float* fsin = (fa[0] > 0.5f) ? fb : fa;
    int tid = blockIdx.x * blockDim.x + threadIdx.x;
    int m  = tid / 1536;
    int d2 = tid - m * 1536;
    int n  = d2 * 2;
    int b  = m >> 11, t = m & 2047;
    u16x2 in = *(const u16x2*)(qkv + (size_t)m * 3072 + n);
    if (n < 2048) {
        int nn = n & 1023;
        int h = nn >> 6, d = nn & 63;
        int i = d >> 1;
        float c = fcos[t * 32 + i], s = fsin[t * 32 + i];
        float re = bf2f(in[0]), im = bf2f(in[1]);
        u16x2 o; o[0] = f2bf(re * c - im * s); o[1] = f2bf(re * s + im * c);
        unsigned short* dst = (n < 1024) ? Qo : Ko;
        *(u16x2*)(dst + ((size_t)((b * 16 + h) * 2048 + t)) * 64 + d) = o;
    } else {
        int nn = n - 2048;
        int h = nn >> 6, d = nn & 63;
        size_t base = ((size_t)((b * 16 + h) * 64 + d)) * 2048 + t;
        Vt[base]        = in[0];
        Vt[base + 2048] = in[1];
    }
}

// ---------------- block-cooperative LDS flash attention (dbuf) ----------------
// 512 blocks = 32 heads x 16 causal pairs. Block with pair-index p owns q-rows
// [64p,64p+64) (lo, diag at kt==p) and [2048-64(p+1), 2048-64p) (hi, end 31-p).
// Complementary-p mapping: bids c and c+256 get p and 15-p -> per-CU work sums
// to 49 iters (uniform). K/V^T tiles double-buffered in LDS; stage kt+1 at loop
// top, one __syncthreads per iter (drains vmcnt).
static __device__ __forceinline__ int swzb(int row, int chunk) {   // LDS byte offset
    return (row << 7) + ((chunk ^ (row & 7)) << 4);
}
static __device__ __forceinline__ bf16x8 pack2(uint2 a, uint2 b) {
    union { unsigned w[4]; bf16x8 v; } u;
    u.w[0] = a.x; u.w[1] = a.y; u.w[2] = b.x; u.w[3] = b.y;
    return u.v;
}

template <bool DIAG>
static __device__ __forceinline__ void softmax64(const f32x4 s[4], int key0, int qrow,
                                                 float& m, float& l,
                                                 f32x4 o[4], bf16x8& pf0, bf16x8& pf1, int g) {
    const float SCL = 0.125f * 1.4426950408889634f;   // HD^-0.5 * log2(e)
    float sv[16];
#pragma unroll
    for (int ks = 0; ks < 4; ks++)
#pragma unroll
        for (int j = 0; j < 4; j++) {
            float x = s[ks][j];
            if (DIAG && (key0 + ks * 16 + 4 * g + j > qrow)) x = NINF;
            sv[ks * 4 + j] = x;
        }
    float t8[8];
#pragma unroll
    for (int i = 0; i < 8; i++) t8[i] = fmaxf(sv[i], sv[i + 8]);
#pragma unroll
    for (int i = 0; i < 4; i++) t8[i] = fmaxf(t8[i], t8[i + 4]);
    float tm = fmaxf(fmaxf(t8[0], t8[1]), fmaxf(t8[2], t8[3]));
    tm = fmaxf(tm, __shfl_xor(tm, 16));
    tm = fmaxf(tm, __shfl_xor(tm, 32));

    float msc;
    if (__all(tm <= m)) {                 // exact skip: alpha == 1 for every row
        msc = m * SCL;
    } else {
        float mnew  = fmaxf(m, tm);
        float alpha = exp2f((m - mnew) * SCL);
        l *= alpha;
#pragma unroll
        for (int ch = 0; ch < 4; ch++) o[ch] *= alpha;
        m = mnew;
        msc = mnew * SCL;
    }
    float p[16];
#pragma unroll
    for (int i = 0; i < 16; i++) p[i] = exp2f(__builtin_fmaf(sv[i], SCL, -msc));
    float ps0 = ((p[0] + p[1]) + (p[2] + p[3])) + ((p[4] + p[5]) + (p[6] + p[7]));
    float ps1 = ((p[8] + p[9]) + (p[10] + p[11])) + ((p[12] + p[13]) + (p[14] + p[15]));
    l += ps0 + ps1;
    union { unsigned w[4]; bf16x8 v; } q0, q1;
    asm("v_cvt_pk_bf16_f32 %0, %1, %2" : "=v"(q0.w[0]) : "v"(p[0]),  "v"(p[1]));
    asm("v_cvt_pk_bf16_f32 %0, %1, %2" : "=v"(q0.w[1]) : "v"(p[2]),  "v"(p[3]));
    asm("v_cvt_pk_bf16_f32 %0, %1, %2" : "=v"(q0.w[2]) : "v"(p[4]),  "v"(p[5]));
    asm("v_cvt_pk_bf16_f32 %0, %1, %2" : "=v"(q0.w[3]) : "v"(p[6]),  "v"(p[7]));
    asm("v_cvt_pk_bf16_f32 %0, %1, %2" : "=v"(q1.w[0]) : "v"(p[8]),  "v"(p[9]));
    asm("v_cvt_pk_bf16_f32 %0, %1, %2" : "=v"(q1.w[1]) : "v"(p[10]), "v"(p[11]));
    asm("v_cvt_pk_bf16_f32 %0, %1, %2" : "=v"(q1.w[2]) : "v"(p[12]), "v"(p[13]));
    asm("v_cvt_pk_bf16_f32 %0, %1, %2" : "=v"(q1.w[3]) : "v"(p[14]), "v"(p[15]));
    pf0 = q0.v; pf1 = q1.v;
}

__global__ __launch_bounds__(256) void attn_fwd(const unsigned short* __restrict__ Q,
                                                const unsigned short* __restrict__ Kk,
                                                const unsigned short* __restrict__ Vt,
                                                unsigned short* __restrict__ O) {
    __shared__ __align__(16) unsigned short Ks[2][4096];   // dbuf: 64 keys x 64 d (swizzled)
    __shared__ __align__(16) unsigned short Vs[2][4096];   // dbuf: 64 d x 64 keys (swizzled)

    const int w    = threadIdx.x >> 6;
    const int lane = threadIdx.x & 63;
    const int l15  = lane & 15, g = lane >> 4;

    // bid = ((bh>>3)*16 + pp)*8 + (bh&7); complementary p for the upper half of
    // the grid so CU c's two blocks (bids c, c+256) sum to uniform work.
    const int bid = blockIdx.x;
    const int idx = bid >> 3;
    const int pp  = idx & 15;
    const int p   = (idx >> 4) >= 2 ? 15 - pp : pp;
    const int bh  = ((idx >> 4) << 3) | (bid & 7);
    const int b   = bh >> 4, h = bh & 15;

    const unsigned short* Qb = Q  + (size_t)bh * T_ * HD_;
    const unsigned short* Kb = Kk + (size_t)bh * T_ * HD_;
    const unsigned short* Vb = Vt + (size_t)bh * HD_ * T_;

    const int qLo = p * 64 + 16 * w + l15;
    const int qHi = 2048 - 64 * (p + 1) + 16 * w + l15;
    bf16x8 qlo0 = *(const bf16x8*)(Qb + (size_t)qLo * 64 + 8 * g);
    bf16x8 qlo1 = *(const bf16x8*)(Qb + (size_t)qLo * 64 + 32 + 8 * g);
    bf16x8 qhi0 = *(const bf16x8*)(Qb + (size_t)qHi * 64 + 8 * g);
    bf16x8 qhi1 = *(const bf16x8*)(Qb + (size_t)qHi * 64 + 32 + 8 * g);

    f32x4 oLo[4], oHi[4];
#pragma unroll
    for (int ch = 0; ch < 4; ch++) { oLo[ch] = (f32x4){0,0,0,0}; oHi[ch] = (f32x4){0,0,0,0}; }
    float mLo = NINF, lLo = 0.f, mHi = NINF, lHi = 0.f;

    // staging: unit u -> LDS elems [u*8,u*8+8) = tile slot (row u>>3, chunk u&7);
    // source chunk = (u&7) ^ (row&7)  => LDS slot (r,c) holds global chunk (r, c^(r&7)).
    const int t   = threadIdx.x;
    const int r0  = t >> 3;
    const int cs  = (t & 7) ^ (r0 & 7);
    const int t8e = t * 8;
    const unsigned short* sK = Kb + (size_t)r0 * 64 + cs * 8;     // + key0*64 per tile
    const unsigned short* sV = Vb + (size_t)r0 * 2048 + cs * 8;   // + key0 per tile

#define STAGE_TILE(bb, key0_)                                                   \
    do {                                                                        \
        GLOAD_LDS16(sK + (size_t)(key0_) * 64,        &Ks[bb][t8e]);            \
        GLOAD_LDS16(sK + (size_t)((key0_) + 32) * 64, &Ks[bb][2048 + t8e]);     \
        GLOAD_LDS16(sV + (key0_),                     &Vs[bb][t8e]);            \
        GLOAD_LDS16(sV + 32 * 2048 + (key0_),         &Vs[bb][2048 + t8e]);     \
    } while (0)

    const int ktEnd = 31 - p;      // hi diagonal tile index; lo diagonal at kt==p
    STAGE_TILE(0, 0);
    __syncthreads();               // drains vmcnt -> tile 0 ready

    for (int kt = 0; kt <= ktEnd; ++kt) {
        const int key0 = kt * 64;
        const int cur  = kt & 1;
        if (kt < ktEnd) STAGE_TILE(cur ^ 1, key0 + 64);   // prefetch next tile

        const char* KsB = (const char*)&Ks[cur][0];
        const char* VsB = (const char*)&Vs[cur][0];

        // K fragments (shared by both streams): rows ks*16+l15, chunks {g, 4+g}
        bf16x8 kf[4][2];
#pragma unroll
        for (int ks = 0; ks < 4; ks++) {
            int rK = ks * 16 + l15;
            kf[ks][0] = *(const bf16x8*)(KsB + swzb(rK, g));
            kf[ks][1] = *(const bf16x8*)(KsB + swzb(rK, 4 + g));
        }
        // V^T fragments: rows 16ch+l15; b64 at byte (g&1)*8 in chunks {2s + (g>>1)}
        bf16x8 va[4][2];
#pragma unroll
        for (int ch = 0; ch < 4; ch++) {
            int rV = 16 * ch + l15;
            int wo = (g & 1) * 8;
            uint2 s0 = *(const uint2*)(VsB + swzb(rV, (g >> 1))     + wo);
            uint2 s1 = *(const uint2*)(VsB + swzb(rV, 2 + (g >> 1)) + wo);
            uint2 s2 = *(const uint2*)(VsB + swzb(rV, 4 + (g >> 1)) + wo);
            uint2 s3 = *(const uint2*)(VsB + swzb(rV, 6 + (g >> 1)) + wo);
            va[ch][0] = pack2(s0, s1);   // key slots 4g+j, 16+4g+j
            va[ch][1] = pack2(s2, s3);   // key slots 32+4g+j, 48+4g+j
        }

        f32x4 z = (f32x4){0, 0, 0, 0};
        // hi stream (always active)
        {
            f32x4 s[4];
#pragma unroll
            for (int ks = 0; ks < 4; ks++) {
                s[ks] = __builtin_amdgcn_mfma_f32_16x16x32_bf16(kf[ks][0], qhi0, z, 0, 0, 0);
                s[ks] = __builtin_amdgcn_mfma_f32_16x16x32_bf16(kf[ks][1], qhi1, s[ks], 0, 0, 0);
            }
            bf16x8 pf0, pf1;
            if (kt == ktEnd) softmax64<true >(s, key0, qHi, mHi, lHi, oHi, pf0, pf1, g);
            else             softmax64<false>(s, key0, qHi, mHi, lHi, oHi, pf0, pf1, g);
#pragma unroll
            for (int ch = 0; ch < 4; ch++) {
                oHi[ch] = __builtin_amdgcn_mfma_f32_16x16x32_bf16(va[ch][0], pf0, oHi[ch], 0, 0, 0);
                oHi[ch] = __builtin_amdgcn_mfma_f32_16x16x32_bf16(va[ch][1], pf1, oHi[ch], 0, 0, 0);
            }
        }
        // lo stream (block-uniform branch)
        if (kt <= p) {
            f32x4 s[4];
#pragma unroll
            for (int ks = 0; ks < 4; ks++) {
                s[ks] = __builtin_amdgcn_mfma_f32_16x16x32_bf16(kf[ks][0], qlo0, z, 0, 0, 0);
                s[ks] = __builtin_amdgcn_mfma_f32_16x16x32_bf16(kf[ks][1], qlo1, s[ks], 0, 0, 0);
            }
            bf16x8 pf0, pf1;
            if (kt == p) softmax64<true >(s, key0, qLo, mLo, lLo, oLo, pf0, pf1, g);
            else         softmax64<false>(s, key0, qLo, mLo, lLo, oLo, pf0, pf1, g);
#pragma unroll
            for (int ch = 0; ch < 4; ch++) {
                oLo[ch] = __builtin_amdgcn_mfma_f32_16x16x32_bf16(va[ch][0], pf0, oLo[ch], 0, 0, 0);
                oLo[ch] = __builtin_amdgcn_mfma_f32_16x16x32_bf16(va[ch][1], pf1, oLo[ch], 0, 0, 0);
            }
        }

        __syncthreads();    // drains vmcnt (next tile staged) + read/write fence
    }
#undef STAGE_TILE

    lLo += __shfl_xor(lLo, 16); lLo += __shfl_xor(lLo, 32);
    lHi += __shfl_xor(lHi, 16); lHi += __shfl_xor(lHi, 32);
    float invLo = 1.f / lLo, invHi = 1.f / lHi;

    size_t oLoB = (((size_t)b * T_ + qLo) * H_ + h) * HD_;
    size_t oHiB = (((size_t)b * T_ + qHi) * H_ + h) * HD_;
#pragma unroll
    for (int ch = 0; ch < 4; ch++) {
        int d0 = 16 * ch + 4 * g;
        u16x4 va_, vb_;
#pragma unroll
        for (int jj = 0; jj < 4; jj++) {
            va_[jj] = f2bf(oLo[ch][jj] * invLo);
            vb_[jj] = f2bf(oHi[ch][jj] * invHi);
        }
        *(u16x4*)(O + oLoB + d0) = va_;
        *(u16x4*)(O + oHiB + d0) = vb_;
    }
}

extern "C" void kernel_launch(void* const* d_in, const int* in_sizes, int n_in,
                              void* d_out, int out_size, void* d_ws, size_t ws_size,
                              hipStream_t stream) {
    (void)out_size;
    const float *x = nullptr, *wqkv = nullptr, *wproj = nullptr, *bproj = nullptr;
    const float *fa = nullptr, *fb = nullptr;
    for (int i = 0; i < n_in; i++) {
        switch (in_sizes[i]) {
            case 4194304: x     = (const float*)d_in[i]; break;
            case 3145728: wqkv  = (const float*)d_in[i]; break;
            case 1048576: wproj = (const float*)d_in[i]; break;
            case 1024:    bproj = (const float*)d_in[i]; break;
            case 65536:   if (!fa) fa = (const float*)d_in[i]; else fb = (const float*)d_in[i]; break;
            default: break;
        }
    }
    if (!x || !wqkv || !wproj || !bproj || !fa || !fb) return;
    if (ws_size < (size_t)48 * 1024 * 1024) return;

    char* ws = (char*)d_ws;
    const size_t MB = 1024 * 1024;
    unsigned short* qkv    = (unsigned short*)(ws);            // [0,24M)
    unsigned short* oat    = (unsigned short*)(ws);            // [0,8M)   (after rope)
    unsigned short* wprojb = (unsigned short*)(ws + 8  * MB);  // [8,10M)  (after rope)
    unsigned short* xb     = (unsigned short*)(ws + 24 * MB);  // [24,32M)
    unsigned short* wqkvb  = (unsigned short*)(ws + 32 * MB);  // [32,38M)
    unsigned short* qro    = (unsigned short*)(ws + 24 * MB);  // [24,32M)
    unsigned short* kro    = (unsigned short*)(ws + 32 * MB);  // [32,40M)
    unsigned short* vt     = (unsigned short*)(ws + 40 * MB);  // [40,48M)

    convert_f32_bf16<<<4096, 256, 0, stream>>>(x,    xb,    4194304 / 4);
    convert_f32_bf16<<<3072, 256, 0, stream>>>(wqkv, wqkvb, 3145728 / 4);

    gemm_nt<<<dim3(3072 / 128, 4096 / 128), 256, 0, stream>>>(xb, wqkvb, qkv, nullptr,
                                                              4096, 3072, 1024, 0);

    rope_split<<<(4096 * 1536) / 256, 256, 0, stream>>>(qkv, fa, fb, qro, kro, vt);

    convert_f32_bf16<<<1024, 256, 0, stream>>>(wproj, wprojb, 1048576 / 4);

    attn_fwd<<<512, 256, 0, stream>>>(qro, kro, vt, oat);

    gemm_nt<<<dim3(1024 / 128, 4096 / 128), 256, 0, stream>>>(oat, wprojb, d_out, bproj,
                                                              4096, 1024, 1024, 1);
}

// Round 10
// 161.654 us; speedup vs baseline: 2.0160x; 1.0402x over previous
//
#include <hip/hip_runtime.h>

// B=2, T=2048, C=1024, H=16, HD=64. Inputs f32, output f32.
// convert->bf16, QKV GEMM (MFMA + global_load_lds), RoPE+split (+V^T),
// flash attention: 1024 blocks x 4 waves, ONE 16-row q-block per wave,
// per-CU-balanced r mapping {z,15-z,16+z,31-z}, XCD-grouped heads, LDS dbuf,
// defer-max softmax, swapped-QK^T MFMA. proj GEMM -> f32.
// ws plan (48 MiB):
//   [0,24M)  qkv   -> dead after rope; [0,8M) attn out, [8,10M) W_proj bf16
//   [24,32M) xb    -> dead after gemm1; reused as Q (B,H,T,64)
//   [32,38M) wqkvb -> dead after gemm1; reused as K (B,H,T,64) [32,40M)
//   [40,48M) V^T   (B,H,64,T)

typedef short  bf16x8 __attribute__((ext_vector_type(8)));
typedef float  f32x4  __attribute__((ext_vector_type(4)));
typedef unsigned short u16x4 __attribute__((ext_vector_type(4)));
typedef unsigned short u16x2 __attribute__((ext_vector_type(2)));

#define B_  2
#define T_  2048
#define H_  16
#define HD_ 64
#define NINF (-__builtin_inff())

static __device__ __forceinline__ unsigned short f2bf(float f) {
    union { float f; unsigned u; } v; v.f = f;
    unsigned r = v.u + 0x7fffu + ((v.u >> 16) & 1u);   // RNE
    return (unsigned short)(r >> 16);
}
static __device__ __forceinline__ float bf2f(unsigned short s) {
    union { unsigned u; float f; } v; v.u = ((unsigned)s) << 16;
    return v.f;
}

#define GLOAD_LDS16(gp, lp)                                                              \
    __builtin_amdgcn_global_load_lds((const __attribute__((address_space(1))) void*)(gp), \
                                     (__attribute__((address_space(3))) void*)(lp), 16, 0, 0)

// ---------------- f32 -> bf16 convert (vector x4) ----------------
__global__ void convert_f32_bf16(const float* __restrict__ in,
                                 unsigned short* __restrict__ out, int n4) {
    int i = blockIdx.x * blockDim.x + threadIdx.x;
    if (i >= n4) return;
    float4 f = ((const float4*)in)[i];
    u16x4 o; o[0] = f2bf(f.x); o[1] = f2bf(f.y); o[2] = f2bf(f.z); o[3] = f2bf(f.w);
    ((u16x4*)out)[i] = o;
}

// ---------------- GEMM (m97 structure): C[m][n] = sum_k A[m][k]*B[n][k] (+bias) ---
__global__ __launch_bounds__(256) void gemm_nt(const unsigned short* __restrict__ A,
                                               const unsigned short* __restrict__ Bm,
                                               void* __restrict__ Cm,
                                               const float* __restrict__ bias,
                                               int M, int N, int K, int out_f32) {
    __shared__ __align__(16) unsigned short As[128 * 32];
    __shared__ __align__(16) unsigned short Bs[128 * 32];
    const int tid  = threadIdx.x;
    const int w    = tid >> 6;
    const int lane = tid & 63;
    const int r    = lane & 15, g = lane >> 4;
    const int m0   = blockIdx.y * 128;
    const int n0   = blockIdx.x * 128;
    const int wm   = (w >> 1) * 64, wn = (w & 1) * 64;

    f32x4 acc[4][4];
#pragma unroll
    for (int i = 0; i < 4; i++)
#pragma unroll
        for (int j = 0; j < 4; j++) acc[i][j] = (f32x4){0.f, 0.f, 0.f, 0.f};

    const int u0 = tid, u1 = 256 + tid;
    const unsigned short* ga0 = A  + (size_t)(m0 + (u0 >> 2)) * K + (u0 & 3) * 8;
    const unsigned short* ga1 = A  + (size_t)(m0 + (u1 >> 2)) * K + (u1 & 3) * 8;
    const unsigned short* gb0 = Bm + (size_t)(n0 + (u0 >> 2)) * K + (u0 & 3) * 8;
    const unsigned short* gb1 = Bm + (size_t)(n0 + (u1 >> 2)) * K + (u1 & 3) * 8;
    unsigned short* la0 = &As[(w * 64) * 8];
    unsigned short* la1 = &As[(256 + w * 64) * 8];
    unsigned short* lb0 = &Bs[(w * 64) * 8];
    unsigned short* lb1 = &Bs[(256 + w * 64) * 8];

    for (int k0 = 0; k0 < K; k0 += 32) {
        __syncthreads();
        GLOAD_LDS16(ga0 + k0, la0);
        GLOAD_LDS16(ga1 + k0, la1);
        GLOAD_LDS16(gb0 + k0, lb0);
        GLOAD_LDS16(gb1 + k0, lb1);
        __syncthreads();

        bf16x8 a[4], b[4];
#pragma unroll
        for (int mi = 0; mi < 4; mi++) a[mi] = *(const bf16x8*)&As[(wm + mi * 16 + r) * 32 + 8 * g];
#pragma unroll
        for (int ni = 0; ni < 4; ni++) b[ni] = *(const bf16x8*)&Bs[(wn + ni * 16 + r) * 32 + 8 * g];
#pragma unroll
        for (int mi = 0; mi < 4; mi++)
#pragma unroll
            for (int ni = 0; ni < 4; ni++)
                acc[mi][ni] = __builtin_amdgcn_mfma_f32_16x16x32_bf16(a[mi], b[ni], acc[mi][ni], 0, 0, 0);
    }

#pragma unroll
    for (int mi = 0; mi < 4; mi++) {
        int row = m0 + wm + mi * 16 + 4 * g;
#pragma unroll
        for (int ni = 0; ni < 4; ni++) {
            int col = n0 + wn + ni * 16 + r;
            float bv = bias ? bias[col] : 0.f;
#pragma unroll
            for (int j = 0; j < 4; j++) {
                float v = acc[mi][ni][j] + bv;
                size_t idx = (size_t)(row + j) * N + col;
                if (out_f32) ((float*)Cm)[idx] = v;
                else         ((unsigned short*)Cm)[idx] = f2bf(v);
            }
        }
    }
}

// ---------------- RoPE + split qkv -> Q,K (B,H,T,HD) and V^T (B,H,HD,T) ----------------
__global__ void rope_split(const unsigned short* __restrict__ qkv,
                           const float* __restrict__ fa, const float* __restrict__ fb,
                           unsigned short* __restrict__ Qo, unsigned short* __restrict__ Ko,
                           unsigned short* __restrict__ Vt) {
    const float* fcos = (fa[0] > 0.5f) ? fa : fb;   // cos row at t=0 is all 1.0
    const float* fsin = (fa[0] > 0.5f) ? fb : fa;
    int tid = blockIdx.x * blockDim.x + threadIdx.x;
    int m  = tid / 1536;
    int d2 = tid - m * 1536;
    int n  = d2 * 2;
    int b  = m >> 11, t = m & 2047;
    u16x2 in = *(const u16x2*)(qkv + (size_t)m * 3072 + n);
    if (n < 2048) {
        int nn = n & 1023;
        int h = nn >> 6, d = nn & 63;
        int i = d >> 1;
        float c = fcos[t * 32 + i], s = fsin[t * 32 + i];
        float re = bf2f(in[0]), im = bf2f(in[1]);
        u16x2 o; o[0] = f2bf(re * c - im * s); o[1] = f2bf(re * s + im * c);
        unsigned short* dst = (n < 1024) ? Qo : Ko;
        *(u16x2*)(dst + ((size_t)((b * 16 + h) * 2048 + t)) * 64 + d) = o;
    } else {
        int nn = n - 2048;
        int h = nn >> 6, d = nn & 63;
        size_t base = ((size_t)((b * 16 + h) * 64 + d)) * 2048 + t;
        Vt[base]        = in[0];
        Vt[base + 2048] = in[1];
    }
}

// ---------------- flash attention: 1 q-block (16 rows) per wave, 1024 blocks ----
// bid -> xcd=bid&7, y=(bid>>3)&31, q=bid>>8. bh = xcd | ((y&3)<<3) (4 heads/XCD,
// K+V 2MB -> L2-resident). z=y>>2; r = {z, 15-z, 16+z, 31-z}[q] -> each CU's four
// blocks have trip counts summing to 66 (uniform). Block r covers q-rows
// [64r,64r+64); wave w owns rows [64r+16w,+16); all waves diag at kt==r.
static __device__ __forceinline__ int swzb(int row, int chunk) {   // LDS byte offset
    return (row << 7) + ((chunk ^ (row & 7)) << 4);
}
static __device__ __forceinline__ bf16x8 pack2(uint2 a, uint2 b) {
    union { unsigned w[4]; bf16x8 v; } u;
    u.w[0] = a.x; u.w[1] = a.y; u.w[2] = b.x; u.w[3] = b.y;
    return u.v;
}

template <bool DIAG>
static __device__ __forceinline__ void softmax64(const f32x4 s[4], int key0, int qrow,
                                                 float& m, float& l,
                                                 f32x4 o[4], bf16x8& pf0, bf16x8& pf1, int g) {
    const float SCL = 0.125f * 1.4426950408889634f;   // HD^-0.5 * log2(e)
    float sv[16];
#pragma unroll
    for (int ks = 0; ks < 4; ks++)
#pragma unroll
        for (int j = 0; j < 4; j++) {
            float x = s[ks][j];
            if (DIAG && (key0 + ks * 16 + 4 * g + j > qrow)) x = NINF;
            sv[ks * 4 + j] = x;
        }
    float t8[8];
#pragma unroll
    for (int i = 0; i < 8; i++) t8[i] = fmaxf(sv[i], sv[i + 8]);
#pragma unroll
    for (int i = 0; i < 4; i++) t8[i] = fmaxf(t8[i], t8[i + 4]);
    float tm = fmaxf(fmaxf(t8[0], t8[1]), fmaxf(t8[2], t8[3]));
    tm = fmaxf(tm, __shfl_xor(tm, 16));
    tm = fmaxf(tm, __shfl_xor(tm, 32));

    float msc;
    if (__all(tm <= m)) {                 // exact skip: alpha == 1 for every row
        msc = m * SCL;
    } else {
        float mnew  = fmaxf(m, tm);
        float alpha = exp2f((m - mnew) * SCL);
        l *= alpha;
#pragma unroll
        for (int ch = 0; ch < 4; ch++) o[ch] *= alpha;
        m = mnew;
        msc = mnew * SCL;
    }
    float p[16];
#pragma unroll
    for (int i = 0; i < 16; i++) p[i] = exp2f(__builtin_fmaf(sv[i], SCL, -msc));
    float ps0 = ((p[0] + p[1]) + (p[2] + p[3])) + ((p[4] + p[5]) + (p[6] + p[7]));
    float ps1 = ((p[8] + p[9]) + (p[10] + p[11])) + ((p[12] + p[13]) + (p[14] + p[15]));
    l += ps0 + ps1;
    union { unsigned w[4]; bf16x8 v; } q0, q1;
    asm("v_cvt_pk_bf16_f32 %0, %1, %2" : "=v"(q0.w[0]) : "v"(p[0]),  "v"(p[1]));
    asm("v_cvt_pk_bf16_f32 %0, %1, %2" : "=v"(q0.w[1]) : "v"(p[2]),  "v"(p[3]));
    asm("v_cvt_pk_bf16_f32 %0, %1, %2" : "=v"(q0.w[2]) : "v"(p[4]),  "v"(p[5]));
    asm("v_cvt_pk_bf16_f32 %0, %1, %2" : "=v"(q0.w[3]) : "v"(p[6]),  "v"(p[7]));
    asm("v_cvt_pk_bf16_f32 %0, %1, %2" : "=v"(q1.w[0]) : "v"(p[8]),  "v"(p[9]));
    asm("v_cvt_pk_bf16_f32 %0, %1, %2" : "=v"(q1.w[1]) : "v"(p[10]), "v"(p[11]));
    asm("v_cvt_pk_bf16_f32 %0, %1, %2" : "=v"(q1.w[2]) : "v"(p[12]), "v"(p[13]));
    asm("v_cvt_pk_bf16_f32 %0, %1, %2" : "=v"(q1.w[3]) : "v"(p[14]), "v"(p[15]));
    pf0 = q0.v; pf1 = q1.v;
}

__global__ __launch_bounds__(256, 4) void attn_fwd(const unsigned short* __restrict__ Q,
                                                   const unsigned short* __restrict__ Kk,
                                                   const unsigned short* __restrict__ Vt,
                                                   unsigned short* __restrict__ O) {
    __shared__ __align__(16) unsigned short Ks[2][4096];   // dbuf: 64 keys x 64 d (swizzled)
    __shared__ __align__(16) unsigned short Vs[2][4096];   // dbuf: 64 d x 64 keys (swizzled)

    const int w    = threadIdx.x >> 6;
    const int lane = threadIdx.x & 63;
    const int l15  = lane & 15, g = lane >> 4;

    const int bid = blockIdx.x;
    const int x   = bid & 7;
    const int y   = (bid >> 3) & 31;
    const int q   = bid >> 8;                 // 0..3
    const int bh  = x | ((y & 3) << 3);       // 32 bh, 4 per XCD
    const int z   = y >> 2;                   // 0..7
    const int r   = (q == 0) ? z : (q == 1) ? 15 - z : (q == 2) ? 16 + z : 31 - z;
    const int b   = bh >> 4, h = bh & 15;

    const unsigned short* Qb = Q  + (size_t)bh * T_ * HD_;
    const unsigned short* Kb = Kk + (size_t)bh * T_ * HD_;
    const unsigned short* Vb = Vt + (size_t)bh * HD_ * T_;

    const int qrow = r * 64 + 16 * w + l15;
    bf16x8 qf0 = *(const bf16x8*)(Qb + (size_t)qrow * 64 + 8 * g);
    bf16x8 qf1 = *(const bf16x8*)(Qb + (size_t)qrow * 64 + 32 + 8 * g);

    f32x4 o[4];
#pragma unroll
    for (int ch = 0; ch < 4; ch++) o[ch] = (f32x4){0, 0, 0, 0};
    float m2 = NINF, lsum = 0.f;

    // staging: unit u -> LDS elems [u*8,u*8+8) = tile slot (row u>>3, chunk u&7);
    // source chunk = (u&7) ^ (row&7)  => LDS slot (rr,c) holds global chunk (rr, c^(rr&7)).
    const int t   = threadIdx.x;
    const int r0  = t >> 3;
    const int cs  = (t & 7) ^ (r0 & 7);
    const int t8e = t * 8;
    const unsigned short* sK = Kb + (size_t)r0 * 64 + cs * 8;     // + key0*64 per tile
    const unsigned short* sV = Vb + (size_t)r0 * 2048 + cs * 8;   // + key0 per tile

#define STAGE_TILE(bb, key0_)                                                   \
    do {                                                                        \
        GLOAD_LDS16(sK + (size_t)(key0_) * 64,        &Ks[bb][t8e]);            \
        GLOAD_LDS16(sK + (size_t)((key0_) + 32) * 64, &Ks[bb][2048 + t8e]);     \
        GLOAD_LDS16(sV + (key0_),                     &Vs[bb][t8e]);            \
        GLOAD_LDS16(sV + 32 * 2048 + (key0_),         &Vs[bb][2048 + t8e]);     \
    } while (0)

    STAGE_TILE(0, 0);
    __syncthreads();               // drains vmcnt -> tile 0 ready

    for (int kt = 0; kt <= r; ++kt) {
        const int key0 = kt * 64;
        const int cur  = kt & 1;
        if (kt < r) STAGE_TILE(cur ^ 1, key0 + 64);   // prefetch next tile

        const char* KsB = (const char*)&Ks[cur][0];
        const char* VsB = (const char*)&Vs[cur][0];

        // K fragments: rows ks*16+l15, chunks {g, 4+g}
        bf16x8 kf[4][2];
#pragma unroll
        for (int ks = 0; ks < 4; ks++) {
            int rK = ks * 16 + l15;
            kf[ks][0] = *(const bf16x8*)(KsB + swzb(rK, g));
            kf[ks][1] = *(const bf16x8*)(KsB + swzb(rK, 4 + g));
        }
        // V^T fragments: rows 16ch+l15; b64 at byte (g&1)*8 in chunks {2s + (g>>1)}
        bf16x8 va[4][2];
#pragma unroll
        for (int ch = 0; ch < 4; ch++) {
            int rV = 16 * ch + l15;
            int wo = (g & 1) * 8;
            uint2 s0 = *(const uint2*)(VsB + swzb(rV, (g >> 1))     + wo);
            uint2 s1 = *(const uint2*)(VsB + swzb(rV, 2 + (g >> 1)) + wo);
            uint2 s2 = *(const uint2*)(VsB + swzb(rV, 4 + (g >> 1)) + wo);
            uint2 s3 = *(const uint2*)(VsB + swzb(rV, 6 + (g >> 1)) + wo);
            va[ch][0] = pack2(s0, s1);   // key slots 4g+j, 16+4g+j
            va[ch][1] = pack2(s2, s3);   // key slots 32+4g+j, 48+4g+j
        }

        f32x4 z4 = (f32x4){0, 0, 0, 0};
        f32x4 s[4];
#pragma unroll
        for (int ks = 0; ks < 4; ks++) {
            s[ks] = __builtin_amdgcn_mfma_f32_16x16x32_bf16(kf[ks][0], qf0, z4, 0, 0, 0);
            s[ks] = __builtin_amdgcn_mfma_f32_16x16x32_bf16(kf[ks][1], qf1, s[ks], 0, 0, 0);
        }

        bf16x8 pf0, pf1;
        if (kt == r) softmax64<true >(s, key0, qrow, m2, lsum, o, pf0, pf1, g);
        else         softmax64<false>(s, key0, qrow, m2, lsum, o, pf0, pf1, g);

#pragma unroll
        for (int ch = 0; ch < 4; ch++) {
            o[ch] = __builtin_amdgcn_mfma_f32_16x16x32_bf16(va[ch][0], pf0, o[ch], 0, 0, 0);
            o[ch] = __builtin_amdgcn_mfma_f32_16x16x32_bf16(va[ch][1], pf1, o[ch], 0, 0, 0);
        }

        __syncthreads();    // drains vmcnt (next tile staged) + read/write fence
    }
#undef STAGE_TILE

    lsum += __shfl_xor(lsum, 16);
    lsum += __shfl_xor(lsum, 32);
    float inv = 1.f / lsum;

    size_t obase = (((size_t)b * T_ + qrow) * H_ + h) * HD_;
#pragma unroll
    for (int ch = 0; ch < 4; ch++) {
        int d0 = 16 * ch + 4 * g;
        u16x4 ov;
#pragma unroll
        for (int jj = 0; jj < 4; jj++) ov[jj] = f2bf(o[ch][jj] * inv);
        *(u16x4*)(O + obase + d0) = ov;
    }
}

extern "C" void kernel_launch(void* const* d_in, const int* in_sizes, int n_in,
                              void* d_out, int out_size, void* d_ws, size_t ws_size,
                              hipStream_t stream) {
    (void)out_size;
    const float *x = nullptr, *wqkv = nullptr, *wproj = nullptr, *bproj = nullptr;
    const float *fa = nullptr, *fb = nullptr;
    for (int i = 0; i < n_in; i++) {
        switch (in_sizes[i]) {
            case 4194304: x     = (const float*)d_in[i]; break;
            case 3145728: wqkv  = (const float*)d_in[i]; break;
            case 1048576: wproj = (const float*)d_in[i]; break;
            case 1024:    bproj = (const float*)d_in[i]; break;
            case 65536:   if (!fa) fa = (const float*)d_in[i]; else fb = (const float*)d_in[i]; break;
            default: break;
        }
    }
    if (!x || !wqkv || !wproj || !bproj || !fa || !fb) return;
    if (ws_size < (size_t)48 * 1024 * 1024) return;

    char* ws = (char*)d_ws;
    const size_t MB = 1024 * 1024;
    unsigned short* qkv    = (unsigned short*)(ws);            // [0,24M)
    unsigned short* oat    = (unsigned short*)(ws);            // [0,8M)   (after rope)
    unsigned short* wprojb = (unsigned short*)(ws + 8  * MB);  // [8,10M)  (after rope)
    unsigned short* xb     = (unsigned short*)(ws + 24 * MB);  // [24,32M)
    unsigned short* wqkvb  = (unsigned short*)(ws + 32 * MB);  // [32,38M)
    unsigned short* qro    = (unsigned short*)(ws + 24 * MB);  // [24,32M)
    unsigned short* kro    = (unsigned short*)(ws + 32 * MB);  // [32,40M)
    unsigned short* vt     = (unsigned short*)(ws + 40 * MB);  // [40,48M)

    convert_f32_bf16<<<4096, 256, 0, stream>>>(x,    xb,    4194304 / 4);
    convert_f32_bf16<<<3072, 256, 0, stream>>>(wqkv, wqkvb, 3145728 / 4);

    gemm_nt<<<dim3(3072 / 128, 4096 / 128), 256, 0, stream>>>(xb, wqkvb, qkv, nullptr,
                                                              4096, 3072, 1024, 0);

    rope_split<<<(4096 * 1536) / 256, 256, 0, stream>>>(qkv, fa, fb, qro, kro, vt);

    convert_f32_bf16<<<1024, 256, 0, stream>>>(wproj, wprojb, 1048576 / 4);

    attn_fwd<<<1024, 256, 0, stream>>>(qro, kro, vt, oat);

    gemm_nt<<<dim3(1024 / 128, 4096 / 128), 256, 0, stream>>>(oat, wprojb, d_out, bproj,
                                                              4096, 1024, 1024, 1);
}

// Round 11
// 143.837 us; speedup vs baseline: 2.2658x; 1.1239x over previous
//
#include <hip/hip_runtime.h>

// B=2, T=2048, C=1024, H=16, HD=64. Inputs f32, output f32.
// convert3 (x,Wqkv,Wproj -> bf16, one launch), QKV GEMM with FUSED RoPE+split
// epilogue (Q,K roped -> (B,H,T,64); V -> V^T (B,H,64,T); no qkv intermediate),
// flash attention (r10 structure), proj GEMM -> f32.
// ws plan (48 MiB, no aliasing):
//   [0,8M) xb | [8,14M) wqkvb | [14,16M) wprojb | [16,24M) qro | [24,32M) kro
//   [32,40M) vt | [40,48M) oat

typedef short  bf16x8 __attribute__((ext_vector_type(8)));
typedef float  f32x4  __attribute__((ext_vector_type(4)));
typedef unsigned short u16x4 __attribute__((ext_vector_type(4)));

#define B_  2
#define T_  2048
#define H_  16
#define HD_ 64
#define NINF (-__builtin_inff())

static __device__ __forceinline__ unsigned short f2bf(float f) {
    union { float f; unsigned u; } v; v.f = f;
    unsigned r = v.u + 0x7fffu + ((v.u >> 16) & 1u);   // RNE
    return (unsigned short)(r >> 16);
}

#define GLOAD_LDS16(gp, lp)                                                              \
    __builtin_amdgcn_global_load_lds((const __attribute__((address_space(1))) void*)(gp), \
                                     (__attribute__((address_space(3))) void*)(lp), 16, 0, 0)

// ---------------- single-launch f32 -> bf16 convert of x, W_qkv, W_proj ----------------
__global__ void convert3(const float* __restrict__ x, const float* __restrict__ wqkv,
                         const float* __restrict__ wproj,
                         unsigned short* __restrict__ xb, unsigned short* __restrict__ wqkvb,
                         unsigned short* __restrict__ wprojb) {
    int i = blockIdx.x * blockDim.x + threadIdx.x;     // float4 index, total 2097152
    const float* src; unsigned short* dst; int off;
    if (i < 1048576)      { src = x;     dst = xb;     off = i; }
    else if (i < 1835008) { src = wqkv;  dst = wqkvb;  off = i - 1048576; }
    else                  { src = wproj; dst = wprojb; off = i - 1835008; }
    float4 f = ((const float4*)src)[off];
    u16x4 o; o[0] = f2bf(f.x); o[1] = f2bf(f.y); o[2] = f2bf(f.z); o[3] = f2bf(f.w);
    ((u16x4*)dst)[off] = o;
}

// ---------------- QKV GEMM with fused RoPE+split epilogue ----------------
// A: 4096x1024 bf16 (x), Bm: 3072x1024 bf16 (W_qkv). 128x128 tiles, BK=32,
// global_load_lds staging (m97 structure). Epilogue by region (block-uniform):
//   cols [0,1024):   Q + RoPE -> Qo (B,H,T,64)
//   cols [1024,2048): K + RoPE -> Ko (B,H,T,64)
//   cols [2048,3072): V -> Vt (B,H,64,T)  (8B stores along t)
// RoPE pairing: pair (d,d+1) lives in lanes (r,r+1) -> __shfl_xor(v,1).
__global__ __launch_bounds__(256) void gemm_qkv(const unsigned short* __restrict__ A,
                                                const unsigned short* __restrict__ Bm,
                                                const float* __restrict__ fa,
                                                const float* __restrict__ fb,
                                                unsigned short* __restrict__ Qo,
                                                unsigned short* __restrict__ Ko,
                                                unsigned short* __restrict__ Vt) {
    __shared__ __align__(16) unsigned short As[128 * 32];
    __shared__ __align__(16) unsigned short Bs[128 * 32];
    const int K = 1024;
    const int tid  = threadIdx.x;
    const int w    = tid >> 6;
    const int lane = tid & 63;
    const int r    = lane & 15, g = lane >> 4;
    const int m0   = blockIdx.y * 128;
    const int n0   = blockIdx.x * 128;
    const int wm   = (w >> 1) * 64, wn = (w & 1) * 64;

    f32x4 acc[4][4];
#pragma unroll
    for (int i = 0; i < 4; i++)
#pragma unroll
        for (int j = 0; j < 4; j++) acc[i][j] = (f32x4){0.f, 0.f, 0.f, 0.f};

    const int u0 = tid, u1 = 256 + tid;
    const unsigned short* ga0 = A  + (size_t)(m0 + (u0 >> 2)) * K + (u0 & 3) * 8;
    const unsigned short* ga1 = A  + (size_t)(m0 + (u1 >> 2)) * K + (u1 & 3) * 8;
    const unsigned short* gb0 = Bm + (size_t)(n0 + (u0 >> 2)) * K + (u0 & 3) * 8;
    const unsigned short* gb1 = Bm + (size_t)(n0 + (u1 >> 2)) * K + (u1 & 3) * 8;
    unsigned short* la0 = &As[(w * 64) * 8];
    unsigned short* la1 = &As[(256 + w * 64) * 8];
    unsigned short* lb0 = &Bs[(w * 64) * 8];
    unsigned short* lb1 = &Bs[(256 + w * 64) * 8];

    for (int k0 = 0; k0 < K; k0 += 32) {
        __syncthreads();
        GLOAD_LDS16(ga0 + k0, la0);
        GLOAD_LDS16(ga1 + k0, la1);
        GLOAD_LDS16(gb0 + k0, lb0);
        GLOAD_LDS16(gb1 + k0, lb1);
        __syncthreads();

        bf16x8 a[4], b[4];
#pragma unroll
        for (int mi = 0; mi < 4; mi++) a[mi] = *(const bf16x8*)&As[(wm + mi * 16 + r) * 32 + 8 * g];
#pragma unroll
        for (int ni = 0; ni < 4; ni++) b[ni] = *(const bf16x8*)&Bs[(wn + ni * 16 + r) * 32 + 8 * g];
#pragma unroll
        for (int mi = 0; mi < 4; mi++)
#pragma unroll
            for (int ni = 0; ni < 4; ni++)
                acc[mi][ni] = __builtin_amdgcn_mfma_f32_16x16x32_bf16(a[mi], b[ni], acc[mi][ni], 0, 0, 0);
    }

    // -------- fused epilogue --------
    const float* fcos = (fa[0] > 0.5f) ? fa : fb;   // cos row at t=0 is all 1.0
    const float* fsin = (fa[0] > 0.5f) ? fb : fa;
    const int region = n0 >> 10;                    // 0=Q, 1=K, 2=V (block-uniform)

    if (region < 2) {
        unsigned short* dst = region ? Ko : Qo;
        const float sgn = (r & 1) ? 1.f : -1.f;     // out = v*c + sgn*vp*s
#pragma unroll
        for (int mi = 0; mi < 4; mi++) {
            int row0 = m0 + wm + mi * 16 + 4 * g;
            int b    = row0 >> 11;
            int t0   = row0 & 2047;
#pragma unroll
            for (int ni = 0; ni < 4; ni++) {
                int nn = (n0 & 1023) + wn + ni * 16 + r;
                int h  = nn >> 6, dd = nn & 63;
                int i  = dd >> 1;
                size_t obase = ((size_t)((b * 16 + h) * 2048 + t0)) * 64 + dd;
#pragma unroll
                for (int j = 0; j < 4; j++) {
                    float c = fcos[(t0 + j) * 32 + i];
                    float s = fsin[(t0 + j) * 32 + i];
                    float v  = acc[mi][ni][j];
                    float vp = __shfl_xor(v, 1);
                    float out = __builtin_fmaf(sgn * vp, s, v * c);
                    dst[obase + (size_t)j * 64] = f2bf(out);
                }
            }
        }
    } else {
#pragma unroll
        for (int mi = 0; mi < 4; mi++) {
            int row0 = m0 + wm + mi * 16 + 4 * g;
            int b    = row0 >> 11;
            int t0   = row0 & 2047;
#pragma unroll
            for (int ni = 0; ni < 4; ni++) {
                int nn = (n0 & 1023) + wn + ni * 16 + r;
                int h  = nn >> 6, dd = nn & 63;
                u16x4 ov;
#pragma unroll
                for (int j = 0; j < 4; j++) ov[j] = f2bf(acc[mi][ni][j]);
                *(u16x4*)(Vt + ((size_t)((b * 16 + h) * 64 + dd)) * 2048 + t0) = ov;
            }
        }
    }
}

// ---------------- proj GEMM: C[m][n] = sum_k A[m][k]*B[n][k] + bias -> f32 ----------------
__global__ __launch_bounds__(256) void gemm_nt(const unsigned short* __restrict__ A,
                                               const unsigned short* __restrict__ Bm,
                                               float* __restrict__ Cm,
                                               const float* __restrict__ bias,
                                               int M, int N, int K) {
    __shared__ __align__(16) unsigned short As[128 * 32];
    __shared__ __align__(16) unsigned short Bs[128 * 32];
    const int tid  = threadIdx.x;
    const int w    = tid >> 6;
    const int lane = tid & 63;
    const int r    = lane & 15, g = lane >> 4;
    const int m0   = blockIdx.y * 128;
    const int n0   = blockIdx.x * 128;
    const int wm   = (w >> 1) * 64, wn = (w & 1) * 64;

    f32x4 acc[4][4];
#pragma unroll
    for (int i = 0; i < 4; i++)
#pragma unroll
        for (int j = 0; j < 4; j++) acc[i][j] = (f32x4){0.f, 0.f, 0.f, 0.f};

    const int u0 = tid, u1 = 256 + tid;
    const unsigned short* ga0 = A  + (size_t)(m0 + (u0 >> 2)) * K + (u0 & 3) * 8;
    const unsigned short* ga1 = A  + (size_t)(m0 + (u1 >> 2)) * K + (u1 & 3) * 8;
    const unsigned short* gb0 = Bm + (size_t)(n0 + (u0 >> 2)) * K + (u0 & 3) * 8;
    const unsigned short* gb1 = Bm + (size_t)(n0 + (u1 >> 2)) * K + (u1 & 3) * 8;
    unsigned short* la0 = &As[(w * 64) * 8];
    unsigned short* la1 = &As[(256 + w * 64) * 8];
    unsigned short* lb0 = &Bs[(w * 64) * 8];
    unsigned short* lb1 = &Bs[(256 + w * 64) * 8];

    for (int k0 = 0; k0 < K; k0 += 32) {
        __syncthreads();
        GLOAD_LDS16(ga0 + k0, la0);
        GLOAD_LDS16(ga1 + k0, la1);
        GLOAD_LDS16(gb0 + k0, lb0);
        GLOAD_LDS16(gb1 + k0, lb1);
        __syncthreads();

        bf16x8 a[4], b[4];
#pragma unroll
        for (int mi = 0; mi < 4; mi++) a[mi] = *(const bf16x8*)&As[(wm + mi * 16 + r) * 32 + 8 * g];
#pragma unroll
        for (int ni = 0; ni < 4; ni++) b[ni] = *(const bf16x8*)&Bs[(wn + ni * 16 + r) * 32 + 8 * g];
#pragma unroll
        for (int mi = 0; mi < 4; mi++)
#pragma unroll
            for (int ni = 0; ni < 4; ni++)
                acc[mi][ni] = __builtin_amdgcn_mfma_f32_16x16x32_bf16(a[mi], b[ni], acc[mi][ni], 0, 0, 0);
    }

#pragma unroll
    for (int mi = 0; mi < 4; mi++) {
        int row = m0 + wm + mi * 16 + 4 * g;
#pragma unroll
        for (int ni = 0; ni < 4; ni++) {
            int col = n0 + wn + ni * 16 + r;
            float bv = bias[col];
#pragma unroll
            for (int j = 0; j < 4; j++)
                Cm[(size_t)(row + j) * N + col] = acc[mi][ni][j] + bv;
        }
    }
}

// ---------------- flash attention (round-10 structure, unchanged) ----------------
static __device__ __forceinline__ int swzb(int row, int chunk) {   // LDS byte offset
    return (row << 7) + ((chunk ^ (row & 7)) << 4);
}
static __device__ __forceinline__ bf16x8 pack2(uint2 a, uint2 b) {
    union { unsigned w[4]; bf16x8 v; } u;
    u.w[0] = a.x; u.w[1] = a.y; u.w[2] = b.x; u.w[3] = b.y;
    return u.v;
}

template <bool DIAG>
static __device__ __forceinline__ void softmax64(const f32x4 s[4], int key0, int qrow,
                                                 float& m, float& l,
                                                 f32x4 o[4], bf16x8& pf0, bf16x8& pf1, int g) {
    const float SCL = 0.125f * 1.4426950408889634f;   // HD^-0.5 * log2(e)
    float sv[16];
#pragma unroll
    for (int ks = 0; ks < 4; ks++)
#pragma unroll
        for (int j = 0; j < 4; j++) {
            float x = s[ks][j];
            if (DIAG && (key0 + ks * 16 + 4 * g + j > qrow)) x = NINF;
            sv[ks * 4 + j] = x;
        }
    float t8[8];
#pragma unroll
    for (int i = 0; i < 8; i++) t8[i] = fmaxf(sv[i], sv[i + 8]);
#pragma unroll
    for (int i = 0; i < 4; i++) t8[i] = fmaxf(t8[i], t8[i + 4]);
    float tm = fmaxf(fmaxf(t8[0], t8[1]), fmaxf(t8[2], t8[3]));
    tm = fmaxf(tm, __shfl_xor(tm, 16));
    tm = fmaxf(tm, __shfl_xor(tm, 32));

    float msc;
    if (__all(tm <= m)) {                 // exact skip: alpha == 1 for every row
        msc = m * SCL;
    } else {
        float mnew  = fmaxf(m, tm);
        float alpha = exp2f((m - mnew) * SCL);
        l *= alpha;
#pragma unroll
        for (int ch = 0; ch < 4; ch++) o[ch] *= alpha;
        m = mnew;
        msc = mnew * SCL;
    }
    float p[16];
#pragma unroll
    for (int i = 0; i < 16; i++) p[i] = exp2f(__builtin_fmaf(sv[i], SCL, -msc));
    float ps0 = ((p[0] + p[1]) + (p[2] + p[3])) + ((p[4] + p[5]) + (p[6] + p[7]));
    float ps1 = ((p[8] + p[9]) + (p[10] + p[11])) + ((p[12] + p[13]) + (p[14] + p[15]));
    l += ps0 + ps1;
    union { unsigned w[4]; bf16x8 v; } q0, q1;
    asm("v_cvt_pk_bf16_f32 %0, %1, %2" : "=v"(q0.w[0]) : "v"(p[0]),  "v"(p[1]));
    asm("v_cvt_pk_bf16_f32 %0, %1, %2" : "=v"(q0.w[1]) : "v"(p[2]),  "v"(p[3]));
    asm("v_cvt_pk_bf16_f32 %0, %1, %2" : "=v"(q0.w[2]) : "v"(p[4]),  "v"(p[5]));
    asm("v_cvt_pk_bf16_f32 %0, %1, %2" : "=v"(q0.w[3]) : "v"(p[6]),  "v"(p[7]));
    asm("v_cvt_pk_bf16_f32 %0, %1, %2" : "=v"(q1.w[0]) : "v"(p[8]),  "v"(p[9]));
    asm("v_cvt_pk_bf16_f32 %0, %1, %2" : "=v"(q1.w[1]) : "v"(p[10]), "v"(p[11]));
    asm("v_cvt_pk_bf16_f32 %0, %1, %2" : "=v"(q1.w[2]) : "v"(p[12]), "v"(p[13]));
    asm("v_cvt_pk_bf16_f32 %0, %1, %2" : "=v"(q1.w[3]) : "v"(p[14]), "v"(p[15]));
    pf0 = q0.v; pf1 = q1.v;
}

__global__ __launch_bounds__(256, 4) void attn_fwd(const unsigned short* __restrict__ Q,
                                                   const unsigned short* __restrict__ Kk,
                                                   const unsigned short* __restrict__ Vt,
                                                   unsigned short* __restrict__ O) {
    __shared__ __align__(16) unsigned short Ks[2][4096];   // dbuf: 64 keys x 64 d (swizzled)
    __shared__ __align__(16) unsigned short Vs[2][4096];   // dbuf: 64 d x 64 keys (swizzled)

    const int w    = threadIdx.x >> 6;
    const int lane = threadIdx.x & 63;
    const int l15  = lane & 15, g = lane >> 4;

    const int bid = blockIdx.x;
    const int x   = bid & 7;
    const int y   = (bid >> 3) & 31;
    const int q   = bid >> 8;                 // 0..3
    const int bh  = x | ((y & 3) << 3);       // 32 bh, 4 per XCD
    const int z   = y >> 2;                   // 0..7
    const int r   = (q == 0) ? z : (q == 1) ? 15 - z : (q == 2) ? 16 + z : 31 - z;
    const int b   = bh >> 4, h = bh & 15;

    const unsigned short* Qb = Q  + (size_t)bh * T_ * HD_;
    const unsigned short* Kb = Kk + (size_t)bh * T_ * HD_;
    const unsigned short* Vb = Vt + (size_t)bh * HD_ * T_;

    const int qrow = r * 64 + 16 * w + l15;
    bf16x8 qf0 = *(const bf16x8*)(Qb + (size_t)qrow * 64 + 8 * g);
    bf16x8 qf1 = *(const bf16x8*)(Qb + (size_t)qrow * 64 + 32 + 8 * g);

    f32x4 o[4];
#pragma unroll
    for (int ch = 0; ch < 4; ch++) o[ch] = (f32x4){0, 0, 0, 0};
    float m2 = NINF, lsum = 0.f;

    const int t   = threadIdx.x;
    const int r0  = t >> 3;
    const int cs  = (t & 7) ^ (r0 & 7);
    const int t8e = t * 8;
    const unsigned short* sK = Kb + (size_t)r0 * 64 + cs * 8;     // + key0*64 per tile
    const unsigned short* sV = Vb + (size_t)r0 * 2048 + cs * 8;   // + key0 per tile

#define STAGE_TILE(bb, key0_)                                                   \
    do {                                                                        \
        GLOAD_LDS16(sK + (size_t)(key0_) * 64,        &Ks[bb][t8e]);            \
        GLOAD_LDS16(sK + (size_t)((key0_) + 32) * 64, &Ks[bb][2048 + t8e]);     \
        GLOAD_LDS16(sV + (key0_),                     &Vs[bb][t8e]);            \
        GLOAD_LDS16(sV + 32 * 2048 + (key0_),         &Vs[bb][2048 + t8e]);     \
    } while (0)

    STAGE_TILE(0, 0);
    __syncthreads();               // drains vmcnt -> tile 0 ready

    for (int kt = 0; kt <= r; ++kt) {
        const int key0 = kt * 64;
        const int cur  = kt & 1;
        if (kt < r) STAGE_TILE(cur ^ 1, key0 + 64);   // prefetch next tile

        const char* KsB = (const char*)&Ks[cur][0];
        const char* VsB = (const char*)&Vs[cur][0];

        bf16x8 kf[4][2];
#pragma unroll
        for (int ks = 0; ks < 4; ks++) {
            int rK = ks * 16 + l15;
            kf[ks][0] = *(const bf16x8*)(KsB + swzb(rK, g));
            kf[ks][1] = *(const bf16x8*)(KsB + swzb(rK, 4 + g));
        }
        bf16x8 va[4][2];
#pragma unroll
        for (int ch = 0; ch < 4; ch++) {
            int rV = 16 * ch + l15;
            int wo = (g & 1) * 8;
            uint2 s0 = *(const uint2*)(VsB + swzb(rV, (g >> 1))     + wo);
            uint2 s1 = *(const uint2*)(VsB + swzb(rV, 2 + (g >> 1)) + wo);
            uint2 s2 = *(const uint2*)(VsB + swzb(rV, 4 + (g >> 1)) + wo);
            uint2 s3 = *(const uint2*)(VsB + swzb(rV, 6 + (g >> 1)) + wo);
            va[ch][0] = pack2(s0, s1);   // key slots 4g+j, 16+4g+j
            va[ch][1] = pack2(s2, s3);   // key slots 32+4g+j, 48+4g+j
        }

        f32x4 z4 = (f32x4){0, 0, 0, 0};
        f32x4 s[4];
#pragma unroll
        for (int ks = 0; ks < 4; ks++) {
            s[ks] = __builtin_amdgcn_mfma_f32_16x16x32_bf16(kf[ks][0], qf0, z4, 0, 0, 0);
            s[ks] = __builtin_amdgcn_mfma_f32_16x16x32_bf16(kf[ks][1], qf1, s[ks], 0, 0, 0);
        }

        bf16x8 pf0, pf1;
        if (kt == r) softmax64<true >(s, key0, qrow, m2, lsum, o, pf0, pf1, g);
        else         softmax64<false>(s, key0, qrow, m2, lsum, o, pf0, pf1, g);

#pragma unroll
        for (int ch = 0; ch < 4; ch++) {
            o[ch] = __builtin_amdgcn_mfma_f32_16x16x32_bf16(va[ch][0], pf0, o[ch], 0, 0, 0);
            o[ch] = __builtin_amdgcn_mfma_f32_16x16x32_bf16(va[ch][1], pf1, o[ch], 0, 0, 0);
        }

        __syncthreads();    // drains vmcnt (next tile staged) + read/write fence
    }
#undef STAGE_TILE

    lsum += __shfl_xor(lsum, 16);
    lsum += __shfl_xor(lsum, 32);
    float inv = 1.f / lsum;

    size_t obase = (((size_t)b * T_ + qrow) * H_ + h) * HD_;
#pragma unroll
    for (int ch = 0; ch < 4; ch++) {
        int d0 = 16 * ch + 4 * g;
        u16x4 ov;
#pragma unroll
        for (int jj = 0; jj < 4; jj++) ov[jj] = f2bf(o[ch][jj] * inv);
        *(u16x4*)(O + obase + d0) = ov;
    }
}

extern "C" void kernel_launch(void* const* d_in, const int* in_sizes, int n_in,
                              void* d_out, int out_size, void* d_ws, size_t ws_size,
                              hipStream_t stream) {
    (void)out_size;
    const float *x = nullptr, *wqkv = nullptr, *wproj = nullptr, *bproj = nullptr;
    const float *fa = nullptr, *fb = nullptr;
    for (int i = 0; i < n_in; i++) {
        switch (in_sizes[i]) {
            case 4194304: x     = (const float*)d_in[i]; break;
            case 3145728: wqkv  = (const float*)d_in[i]; break;
            case 1048576: wproj = (const float*)d_in[i]; break;
            case 1024:    bproj = (const float*)d_in[i]; break;
            case 65536:   if (!fa) fa = (const float*)d_in[i]; else fb = (const float*)d_in[i]; break;
            default: break;
        }
    }
    if (!x || !wqkv || !wproj || !bproj || !fa || !fb) return;
    if (ws_size < (size_t)48 * 1024 * 1024) return;

    char* ws = (char*)d_ws;
    const size_t MB = 1024 * 1024;
    unsigned short* xb     = (unsigned short*)(ws);            // [0,8M)
    unsigned short* wqkvb  = (unsigned short*)(ws + 8  * MB);  // [8,14M)
    unsigned short* wprojb = (unsigned short*)(ws + 14 * MB);  // [14,16M)
    unsigned short* qro    = (unsigned short*)(ws + 16 * MB);  // [16,24M)
    unsigned short* kro    = (unsigned short*)(ws + 24 * MB);  // [24,32M)
    unsigned short* vt     = (unsigned short*)(ws + 32 * MB);  // [32,40M)
    unsigned short* oat    = (unsigned short*)(ws + 40 * MB);  // [40,48M)

    convert3<<<8192, 256, 0, stream>>>(x, wqkv, wproj, xb, wqkvb, wprojb);

    gemm_qkv<<<dim3(24, 32), 256, 0, stream>>>(xb, wqkvb, fa, fb, qro, kro, vt);

    attn_fwd<<<1024, 256, 0, stream>>>(qro, kro, vt, oat);

    gemm_nt<<<dim3(8, 32), 256, 0, stream>>>(oat, wprojb, (float*)d_out, bproj,
                                             4096, 1024, 1024);
}

// Round 12
// 129.689 us; speedup vs baseline: 2.5129x; 1.1091x over previous
//
#include <hip/hip_runtime.h>

// B=2, T=2048, C=1024, H=16, HD=64. Inputs f32, output f32.
// convert3, QKV GEMM + fused RoPE/split epilogue (V^T stored with keys
// pre-permuted to MFMA slot order), flash attention (raw v_exp, precomputed
// LDS offsets, b128 V reads), proj GEMM -> f32.
// ws plan (48 MiB): [0,8M) xb | [8,14M) wqkvb | [14,16M) wprojb | [16,24M) qro
//                   | [24,32M) kro | [32,40M) vt | [40,48M) oat

typedef short  bf16x8 __attribute__((ext_vector_type(8)));
typedef float  f32x4  __attribute__((ext_vector_type(4)));
typedef unsigned short u16x4 __attribute__((ext_vector_type(4)));

#define B_  2
#define T_  2048
#define H_  16
#define HD_ 64
#define NINF (-__builtin_inff())

static __device__ __forceinline__ unsigned short f2bf(float f) {
    union { float f; unsigned u; } v; v.f = f;
    unsigned r = v.u + 0x7fffu + ((v.u >> 16) & 1u);   // RNE
    return (unsigned short)(r >> 16);
}

#define GLOAD_LDS16(gp, lp)                                                              \
    __builtin_amdgcn_global_load_lds((const __attribute__((address_space(1))) void*)(gp), \
                                     (__attribute__((address_space(3))) void*)(lp), 16, 0, 0)

// ---------------- single-launch f32 -> bf16 convert of x, W_qkv, W_proj ----------------
__global__ void convert3(const float* __restrict__ x, const float* __restrict__ wqkv,
                         const float* __restrict__ wproj,
                         unsigned short* __restrict__ xb, unsigned short* __restrict__ wqkvb,
                         unsigned short* __restrict__ wprojb) {
    int i = blockIdx.x * blockDim.x + threadIdx.x;     // float4 index, total 2097152
    const float* src; unsigned short* dst; int off;
    if (i < 1048576)      { src = x;     dst = xb;     off = i; }
    else if (i < 1835008) { src = wqkv;  dst = wqkvb;  off = i - 1048576; }
    else                  { src = wproj; dst = wprojb; off = i - 1835008; }
    float4 f = ((const float4*)src)[off];
    u16x4 o; o[0] = f2bf(f.x); o[1] = f2bf(f.y); o[2] = f2bf(f.z); o[3] = f2bf(f.w);
    ((u16x4*)dst)[off] = o;
}

// ---------------- QKV GEMM with fused RoPE+split epilogue ----------------
// cols [0,1024): Q+RoPE -> Qo (B,H,T,64); [1024,2048): K+RoPE -> Ko;
// [2048,3072): V -> Vt (B,H,64,T) with keys permuted to MFMA slot order
// within each 32-key block: pos(k) = 8*((k&15)>>2) + 4*(k>>4) + (k&3).
__global__ __launch_bounds__(256) void gemm_qkv(const unsigned short* __restrict__ A,
                                                const unsigned short* __restrict__ Bm,
                                                const float* __restrict__ fa,
                                                const float* __restrict__ fb,
                                                unsigned short* __restrict__ Qo,
                                                unsigned short* __restrict__ Ko,
                                                unsigned short* __restrict__ Vt) {
    __shared__ __align__(16) unsigned short As[128 * 32];
    __shared__ __align__(16) unsigned short Bs[128 * 32];
    const int K = 1024;
    const int tid  = threadIdx.x;
    const int w    = tid >> 6;
    const int lane = tid & 63;
    const int r    = lane & 15, g = lane >> 4;
    const int m0   = blockIdx.y * 128;
    const int n0   = blockIdx.x * 128;
    const int wm   = (w >> 1) * 64, wn = (w & 1) * 64;

    f32x4 acc[4][4];
#pragma unroll
    for (int i = 0; i < 4; i++)
#pragma unroll
        for (int j = 0; j < 4; j++) acc[i][j] = (f32x4){0.f, 0.f, 0.f, 0.f};

    const int u0 = tid, u1 = 256 + tid;
    const unsigned short* ga0 = A  + (size_t)(m0 + (u0 >> 2)) * K + (u0 & 3) * 8;
    const unsigned short* ga1 = A  + (size_t)(m0 + (u1 >> 2)) * K + (u1 & 3) * 8;
    const unsigned short* gb0 = Bm + (size_t)(n0 + (u0 >> 2)) * K + (u0 & 3) * 8;
    const unsigned short* gb1 = Bm + (size_t)(n0 + (u1 >> 2)) * K + (u1 & 3) * 8;
    unsigned short* la0 = &As[(w * 64) * 8];
    unsigned short* la1 = &As[(256 + w * 64) * 8];
    unsigned short* lb0 = &Bs[(w * 64) * 8];
    unsigned short* lb1 = &Bs[(256 + w * 64) * 8];

    for (int k0 = 0; k0 < K; k0 += 32) {
        __syncthreads();
        GLOAD_LDS16(ga0 + k0, la0);
        GLOAD_LDS16(ga1 + k0, la1);
        GLOAD_LDS16(gb0 + k0, lb0);
        GLOAD_LDS16(gb1 + k0, lb1);
        __syncthreads();

        bf16x8 a[4], b[4];
#pragma unroll
        for (int mi = 0; mi < 4; mi++) a[mi] = *(const bf16x8*)&As[(wm + mi * 16 + r) * 32 + 8 * g];
#pragma unroll
        for (int ni = 0; ni < 4; ni++) b[ni] = *(const bf16x8*)&Bs[(wn + ni * 16 + r) * 32 + 8 * g];
#pragma unroll
        for (int mi = 0; mi < 4; mi++)
#pragma unroll
            for (int ni = 0; ni < 4; ni++)
                acc[mi][ni] = __builtin_amdgcn_mfma_f32_16x16x32_bf16(a[mi], b[ni], acc[mi][ni], 0, 0, 0);
    }

    // -------- fused epilogue --------
    const float* fcos = (fa[0] > 0.5f) ? fa : fb;   // cos row at t=0 is all 1.0
    const float* fsin = (fa[0] > 0.5f) ? fb : fa;
    const int region = n0 >> 10;                    // 0=Q, 1=K, 2=V (block-uniform)

    if (region < 2) {
        unsigned short* dst = region ? Ko : Qo;
        const float sgn = (r & 1) ? 1.f : -1.f;     // out = v*c + sgn*vp*s
#pragma unroll
        for (int mi = 0; mi < 4; mi++) {
            int row0 = m0 + wm + mi * 16 + 4 * g;
            int b    = row0 >> 11;
            int t0   = row0 & 2047;
#pragma unroll
            for (int ni = 0; ni < 4; ni++) {
                int nn = (n0 & 1023) + wn + ni * 16 + r;
                int h  = nn >> 6, dd = nn & 63;
                int i  = dd >> 1;
                size_t obase = ((size_t)((b * 16 + h) * 2048 + t0)) * 64 + dd;
#pragma unroll
                for (int j = 0; j < 4; j++) {
                    float c = fcos[(t0 + j) * 32 + i];
                    float s = fsin[(t0 + j) * 32 + i];
                    float v  = acc[mi][ni][j];
                    float vp = __shfl_xor(v, 1);
                    float out = __builtin_fmaf(sgn * vp, s, v * c);
                    dst[obase + (size_t)j * 64] = f2bf(out);
                }
            }
        }
    } else {
#pragma unroll
        for (int mi = 0; mi < 4; mi++) {
            int row0 = m0 + wm + mi * 16 + 4 * g;
            int b    = row0 >> 11;
            int t0   = row0 & 2047;
            // key permutation within 32-block (t0 aligned to 4):
            int tp   = (t0 & ~31) + 8 * ((t0 & 15) >> 2) + 4 * ((t0 & 31) >> 4);
#pragma unroll
            for (int ni = 0; ni < 4; ni++) {
                int nn = (n0 & 1023) + wn + ni * 16 + r;
                int h  = nn >> 6, dd = nn & 63;
                u16x4 ov;
#pragma unroll
                for (int j = 0; j < 4; j++) ov[j] = f2bf(acc[mi][ni][j]);
                *(u16x4*)(Vt + ((size_t)((b * 16 + h) * 64 + dd)) * 2048 + tp) = ov;
            }
        }
    }
}

// ---------------- proj GEMM: C[m][n] = sum_k A[m][k]*B[n][k] + bias -> f32 ----------------
__global__ __launch_bounds__(256) void gemm_nt(const unsigned short* __restrict__ A,
                                               const unsigned short* __restrict__ Bm,
                                               float* __restrict__ Cm,
                                               const float* __restrict__ bias,
                                               int M, int N, int K) {
    __shared__ __align__(16) unsigned short As[128 * 32];
    __shared__ __align__(16) unsigned short Bs[128 * 32];
    const int tid  = threadIdx.x;
    const int w    = tid >> 6;
    const int lane = tid & 63;
    const int r    = lane & 15, g = lane >> 4;
    const int m0   = blockIdx.y * 128;
    const int n0   = blockIdx.x * 128;
    const int wm   = (w >> 1) * 64, wn = (w & 1) * 64;

    f32x4 acc[4][4];
#pragma unroll
    for (int i = 0; i < 4; i++)
#pragma unroll
        for (int j = 0; j < 4; j++) acc[i][j] = (f32x4){0.f, 0.f, 0.f, 0.f};

    const int u0 = tid, u1 = 256 + tid;
    const unsigned short* ga0 = A  + (size_t)(m0 + (u0 >> 2)) * K + (u0 & 3) * 8;
    const unsigned short* ga1 = A  + (size_t)(m0 + (u1 >> 2)) * K + (u1 & 3) * 8;
    const unsigned short* gb0 = Bm + (size_t)(n0 + (u0 >> 2)) * K + (u0 & 3) * 8;
    const unsigned short* gb1 = Bm + (size_t)(n0 + (u1 >> 2)) * K + (u1 & 3) * 8;
    unsigned short* la0 = &As[(w * 64) * 8];
    unsigned short* la1 = &As[(256 + w * 64) * 8];
    unsigned short* lb0 = &Bs[(w * 64) * 8];
    unsigned short* lb1 = &Bs[(256 + w * 64) * 8];

    for (int k0 = 0; k0 < K; k0 += 32) {
        __syncthreads();
        GLOAD_LDS16(ga0 + k0, la0);
        GLOAD_LDS16(ga1 + k0, la1);
        GLOAD_LDS16(gb0 + k0, lb0);
        GLOAD_LDS16(gb1 + k0, lb1);
        __syncthreads();

        bf16x8 a[4], b[4];
#pragma unroll
        for (int mi = 0; mi < 4; mi++) a[mi] = *(const bf16x8*)&As[(wm + mi * 16 + r) * 32 + 8 * g];
#pragma unroll
        for (int ni = 0; ni < 4; ni++) b[ni] = *(const bf16x8*)&Bs[(wn + ni * 16 + r) * 32 + 8 * g];
#pragma unroll
        for (int mi = 0; mi < 4; mi++)
#pragma unroll
            for (int ni = 0; ni < 4; ni++)
                acc[mi][ni] = __builtin_amdgcn_mfma_f32_16x16x32_bf16(a[mi], b[ni], acc[mi][ni], 0, 0, 0);
    }

#pragma unroll
    for (int mi = 0; mi < 4; mi++) {
        int row = m0 + wm + mi * 16 + 4 * g;
#pragma unroll
        for (int ni = 0; ni < 4; ni++) {
            int col = n0 + wn + ni * 16 + r;
            float bv = bias[col];
#pragma unroll
            for (int j = 0; j < 4; j++)
                Cm[(size_t)(row + j) * N + col] = acc[mi][ni][j] + bv;
        }
    }
}

// ---------------- flash attention ----------------
// r10 geometry (1024 blocks x 4 waves, balanced r, XCD-grouped heads, dbuf).
// This round: raw v_exp_f32, precomputed LDS byte-offsets (one formula serves
// K and V), V reads = 2 x b128 (keys slot-ordered in memory), unroll-2 kt loop.
static __device__ __forceinline__ int swzb(int row, int chunk) {   // LDS byte offset
    return (row << 7) + ((chunk ^ (row & 7)) << 4);
}

template <bool DIAG>
static __device__ __forceinline__ void softmax64(const f32x4 s[4], int key0, int qrow,
                                                 float& m, float& l,
                                                 f32x4 o[4], bf16x8& pf0, bf16x8& pf1, int g) {
    const float SCL = 0.125f * 1.4426950408889634f;   // HD^-0.5 * log2(e)
    float sv[16];
#pragma unroll
    for (int ks = 0; ks < 4; ks++)
#pragma unroll
        for (int j = 0; j < 4; j++) {
            float x = s[ks][j];
            if (DIAG && (key0 + ks * 16 + 4 * g + j > qrow)) x = NINF;
            sv[ks * 4 + j] = x;
        }
    float t8[8];
#pragma unroll
    for (int i = 0; i < 8; i++) t8[i] = fmaxf(sv[i], sv[i + 8]);
#pragma unroll
    for (int i = 0; i < 4; i++) t8[i] = fmaxf(t8[i], t8[i + 4]);
    float tm = fmaxf(fmaxf(t8[0], t8[1]), fmaxf(t8[2], t8[3]));
    tm = fmaxf(tm, __shfl_xor(tm, 16));
    tm = fmaxf(tm, __shfl_xor(tm, 32));

    float msc;
    if (__all(tm <= m)) {                 // exact skip: alpha == 1 for every row
        msc = m * SCL;
    } else {
        float mnew  = fmaxf(m, tm);
        float alpha = __builtin_amdgcn_exp2f((m - mnew) * SCL);
        l *= alpha;
#pragma unroll
        for (int ch = 0; ch < 4; ch++) o[ch] *= alpha;
        m = mnew;
        msc = mnew * SCL;
    }
    float p[16];
#pragma unroll
    for (int i = 0; i < 16; i++) p[i] = __builtin_amdgcn_exp2f(__builtin_fmaf(sv[i], SCL, -msc));
    float ps0 = ((p[0] + p[1]) + (p[2] + p[3])) + ((p[4] + p[5]) + (p[6] + p[7]));
    float ps1 = ((p[8] + p[9]) + (p[10] + p[11])) + ((p[12] + p[13]) + (p[14] + p[15]));
    l += ps0 + ps1;
    union { unsigned w[4]; bf16x8 v; } q0, q1;
    asm("v_cvt_pk_bf16_f32 %0, %1, %2" : "=v"(q0.w[0]) : "v"(p[0]),  "v"(p[1]));
    asm("v_cvt_pk_bf16_f32 %0, %1, %2" : "=v"(q0.w[1]) : "v"(p[2]),  "v"(p[3]));
    asm("v_cvt_pk_bf16_f32 %0, %1, %2" : "=v"(q0.w[2]) : "v"(p[4]),  "v"(p[5]));
    asm("v_cvt_pk_bf16_f32 %0, %1, %2" : "=v"(q0.w[3]) : "v"(p[6]),  "v"(p[7]));
    asm("v_cvt_pk_bf16_f32 %0, %1, %2" : "=v"(q1.w[0]) : "v"(p[8]),  "v"(p[9]));
    asm("v_cvt_pk_bf16_f32 %0, %1, %2" : "=v"(q1.w[1]) : "v"(p[10]), "v"(p[11]));
    asm("v_cvt_pk_bf16_f32 %0, %1, %2" : "=v"(q1.w[2]) : "v"(p[12]), "v"(p[13]));
    asm("v_cvt_pk_bf16_f32 %0, %1, %2" : "=v"(q1.w[3]) : "v"(p[14]), "v"(p[15]));
    pf0 = q0.v; pf1 = q1.v;
}

__global__ __launch_bounds__(256, 4) void attn_fwd(const unsigned short* __restrict__ Q,
                                                   const unsigned short* __restrict__ Kk,
                                                   const unsigned short* __restrict__ Vt,
                                                   unsigned short* __restrict__ O) {
    __shared__ __align__(16) unsigned short Ks[2][4096];   // dbuf: 64 keys x 64 d (swizzled)
    __shared__ __align__(16) unsigned short Vs[2][4096];   // dbuf: 64 d x 64 keys (swizzled, slot-ordered)

    const int w    = threadIdx.x >> 6;
    const int lane = threadIdx.x & 63;
    const int l15  = lane & 15, g = lane >> 4;

    const int bid = blockIdx.x;
    const int x   = bid & 7;
    const int y   = (bid >> 3) & 31;
    const int q   = bid >> 8;                 // 0..3
    const int bh  = x | ((y & 3) << 3);       // 32 bh, 4 per XCD
    const int z   = y >> 2;                   // 0..7
    const int r   = (q == 0) ? z : (q == 1) ? 15 - z : (q == 2) ? 16 + z : 31 - z;
    const int b   = bh >> 4, h = bh & 15;

    const unsigned short* Qb = Q  + (size_t)bh * T_ * HD_;
    const unsigned short* Kb = Kk + (size_t)bh * T_ * HD_;
    const unsigned short* Vb = Vt + (size_t)bh * HD_ * T_;

    const int qrow = r * 64 + 16 * w + l15;
    bf16x8 qf0 = *(const bf16x8*)(Qb + (size_t)qrow * 64 + 8 * g);
    bf16x8 qf1 = *(const bf16x8*)(Qb + (size_t)qrow * 64 + 32 + 8 * g);

    f32x4 o[4];
#pragma unroll
    for (int ch = 0; ch < 4; ch++) o[ch] = (f32x4){0, 0, 0, 0};
    float m2 = NINF, lsum = 0.f;

    // unified LDS byte-offsets: off[i][hf] = swzb(16i+l15, g or 4+g)
    // (K fragment i=ks uses off[ks][*]; V fragment i=ch uses off[ch][*])
    int off[4][2];
#pragma unroll
    for (int i = 0; i < 4; i++) {
        off[i][0] = swzb(16 * i + l15, g);
        off[i][1] = swzb(16 * i + l15, 4 + g);
    }

    const int t   = threadIdx.x;
    const int r0  = t >> 3;
    const int cs  = (t & 7) ^ (r0 & 7);
    const int t8e = t * 8;
    const unsigned short* sK = Kb + (size_t)r0 * 64 + cs * 8;     // + key0*64 per tile
    const unsigned short* sV = Vb + (size_t)r0 * 2048 + cs * 8;   // + key0 per tile

#define STAGE_TILE(bb, key0_)                                                   \
    do {                                                                        \
        GLOAD_LDS16(sK + (size_t)(key0_) * 64,        &Ks[bb][t8e]);            \
        GLOAD_LDS16(sK + (size_t)((key0_) + 32) * 64, &Ks[bb][2048 + t8e]);     \
        GLOAD_LDS16(sV + (key0_),                     &Vs[bb][t8e]);            \
        GLOAD_LDS16(sV + 32 * 2048 + (key0_),         &Vs[bb][2048 + t8e]);     \
    } while (0)

    STAGE_TILE(0, 0);
    __syncthreads();               // drains vmcnt -> tile 0 ready

#pragma unroll 2
    for (int kt = 0; kt <= r; ++kt) {
        const int key0 = kt * 64;
        const int cur  = kt & 1;
        if (kt < r) STAGE_TILE(cur ^ 1, key0 + 64);   // prefetch next tile

        const char* KsB = (const char*)&Ks[cur][0];
        const char* VsB = (const char*)&Vs[cur][0];

        bf16x8 kf[4][2], va[4][2];
#pragma unroll
        for (int i = 0; i < 4; i++) {
            kf[i][0] = *(const bf16x8*)(KsB + off[i][0]);
            kf[i][1] = *(const bf16x8*)(KsB + off[i][1]);
            va[i][0] = *(const bf16x8*)(VsB + off[i][0]);   // keys slot-ordered in memory
            va[i][1] = *(const bf16x8*)(VsB + off[i][1]);
        }

        f32x4 z4 = (f32x4){0, 0, 0, 0};
        f32x4 s[4];
#pragma unroll
        for (int ks = 0; ks < 4; ks++) {
            s[ks] = __builtin_amdgcn_mfma_f32_16x16x32_bf16(kf[ks][0], qf0, z4, 0, 0, 0);
            s[ks] = __builtin_amdgcn_mfma_f32_16x16x32_bf16(kf[ks][1], qf1, s[ks], 0, 0, 0);
        }

        bf16x8 pf0, pf1;
        if (kt == r) softmax64<true >(s, key0, qrow, m2, lsum, o, pf0, pf1, g);
        else         softmax64<false>(s, key0, qrow, m2, lsum, o, pf0, pf1, g);

#pragma unroll
        for (int ch = 0; ch < 4; ch++) {
            o[ch] = __builtin_amdgcn_mfma_f32_16x16x32_bf16(va[ch][0], pf0, o[ch], 0, 0, 0);
            o[ch] = __builtin_amdgcn_mfma_f32_16x16x32_bf16(va[ch][1], pf1, o[ch], 0, 0, 0);
        }

        __syncthreads();    // drains vmcnt (next tile staged) + read/write fence
    }
#undef STAGE_TILE

    lsum += __shfl_xor(lsum, 16);
    lsum += __shfl_xor(lsum, 32);
    float inv = 1.f / lsum;

    size_t obase = (((size_t)b * T_ + qrow) * H_ + h) * HD_;
#pragma unroll
    for (int ch = 0; ch < 4; ch++) {
        int d0 = 16 * ch + 4 * g;
        u16x4 ov;
#pragma unroll
        for (int jj = 0; jj < 4; jj++) ov[jj] = f2bf(o[ch][jj] * inv);
        *(u16x4*)(O + obase + d0) = ov;
    }
}

extern "C" void kernel_launch(void* const* d_in, const int* in_sizes, int n_in,
                              void* d_out, int out_size, void* d_ws, size_t ws_size,
                              hipStream_t stream) {
    (void)out_size;
    const float *x = nullptr, *wqkv = nullptr, *wproj = nullptr, *bproj = nullptr;
    const float *fa = nullptr, *fb = nullptr;
    for (int i = 0; i < n_in; i++) {
        switch (in_sizes[i]) {
            case 4194304: x     = (const float*)d_in[i]; break;
            case 3145728: wqkv  = (const float*)d_in[i]; break;
            case 1048576: wproj = (const float*)d_in[i]; break;
            case 1024:    bproj = (const float*)d_in[i]; break;
            case 65536:   if (!fa) fa = (const float*)d_in[i]; else fb = (const float*)d_in[i]; break;
            default: break;
        }
    }
    if (!x || !wqkv || !wproj || !bproj || !fa || !fb) return;
    if (ws_size < (size_t)48 * 1024 * 1024) return;

    char* ws = (char*)d_ws;
    const size_t MB = 1024 * 1024;
    unsigned short* xb     = (unsigned short*)(ws);            // [0,8M)
    unsigned short* wqkvb  = (unsigned short*)(ws + 8  * MB);  // [8,14M)
    unsigned short* wprojb = (unsigned short*)(ws + 14 * MB);  // [14,16M)
    unsigned short* qro    = (unsigned short*)(ws + 16 * MB);  // [16,24M)
    unsigned short* kro    = (unsigned short*)(ws + 24 * MB);  // [24,32M)
    unsigned short* vt     = (unsigned short*)(ws + 32 * MB);  // [32,40M)
    unsigned short* oat    = (unsigned short*)(ws + 40 * MB);  // [40,48M)

    convert3<<<8192, 256, 0, stream>>>(x, wqkv, wproj, xb, wqkvb, wprojb);

    gemm_qkv<<<dim3(24, 32), 256, 0, stream>>>(xb, wqkvb, fa, fb, qro, kro, vt);

    attn_fwd<<<1024, 256, 0, stream>>>(qro, kro, vt, oat);

    gemm_nt<<<dim3(8, 32), 256, 0, stream>>>(oat, wprojb, (float*)d_out, bproj,
                                             4096, 1024, 1024);
}